// Round 4
// baseline (242.786 us; speedup 1.0000x reference)
//
#include <hip/hip_runtime.h>
#include <hip/hip_bf16.h>

#define CDIV(a,b) (((a)+(b)-1)/(b))
#define NBUCK_MAX 512   // buckets of 128 nodes; supports N up to 65536 (ebuf packing needs N<=65536)
#define FUSE_CAP 4096   // staged csr entries per fused block (128 nodes, mean 2048)
#define AGGF_CAP 3072   // staged csr entries per k_aggf block (128 nodes)

typedef __attribute__((ext_vector_type(8))) short short8;
typedef __attribute__((ext_vector_type(4))) float f32x4;
typedef __attribute__((ext_vector_type(2))) float f32x2;

static __device__ __forceinline__ unsigned short f2bf(float f){
  union { float f; unsigned u; } v; v.f = f;
  unsigned r = v.u + 0x7fffu + ((v.u >> 16) & 1u);   // RNE
  return (unsigned short)(r >> 16);
}
static __device__ __forceinline__ unsigned pack2(float lo, float hi){
  return (unsigned)f2bf(lo) | ((unsigned)f2bf(hi) << 16);
}
static __device__ __forceinline__ float bf2f(unsigned short s){
  union { unsigned u; float f; } v; v.u = ((unsigned)s) << 16; return v.f;
}
// pack 4 f32 -> 4 fp8 e4m3 bytes (byte0=a .. byte3=d)
static __device__ __forceinline__ unsigned pk_fp8x4(float a, float b, float c, float d){
  int v = __builtin_amdgcn_cvt_pk_fp8_f32(a, b, 0, false);
  v = __builtin_amdgcn_cvt_pk_fp8_f32(c, d, v, true);
  return (unsigned)v;
}

// accumulate 16 fp8 bytes (uint4) into f32x2 accumulators b0..b7 (v_pk_add_f32 path)
#define ACCP16(v) { b0 += __builtin_amdgcn_cvt_pk_f32_fp8((int)v.x, false); \
                    b1 += __builtin_amdgcn_cvt_pk_f32_fp8((int)v.x, true);  \
                    b2 += __builtin_amdgcn_cvt_pk_f32_fp8((int)v.y, false); \
                    b3 += __builtin_amdgcn_cvt_pk_f32_fp8((int)v.y, true);  \
                    b4 += __builtin_amdgcn_cvt_pk_f32_fp8((int)v.z, false); \
                    b5 += __builtin_amdgcn_cvt_pk_f32_fp8((int)v.z, true);  \
                    b6 += __builtin_amdgcn_cvt_pk_f32_fp8((int)v.w, false); \
                    b7 += __builtin_amdgcn_cvt_pk_f32_fp8((int)v.w, true); }

// ---------------- weight pack args ----------------
// perm: first-128 K positions hold channel pi(k) = (k&7)*16 + (k>>3) (matches gemm-epilogue fp8 row layout)

struct WtpArgs {
  const float *W0, *W1, *bl, *g, *b, *rm, *rv;
  unsigned short* Bpk; float *sc; float *sh;
  int kblk, dout, do_bn, nblk, perm;
};

static __device__ __forceinline__ void wtp_one(const WtpArgs& a, int idx){
  int NB16 = a.kblk*32*a.dout;
  if (idx < NB16){
    int j = idx & 7, lane = (idx >> 3) & 63, rest = idx >> 9;
    int NT = a.dout >> 4;
    int nt = rest % NT, kk = rest / NT;
    int nn = nt*16 + (lane & 15);
    int k  = kk*32 + ((lane >> 4) * 8) + j;
    float v;
    if (k < 128){
      int kc = a.perm ? (((k & 7) << 4) | (k >> 3)) : k;
      v = a.W0[nn*128 + kc];
    } else {
      v = a.W1[nn*128 + (k - 128)];
    }
    a.Bpk[idx] = f2bf(v);
  } else if (a.do_bn && idx < NB16 + a.dout){
    int jj = idx - NB16;
    float s = a.g[jj] * rsqrtf(a.rv[jj] + 1e-5f);
    a.sc[jj] = s;
    a.sh[jj] = (a.bl[jj] - a.rm[jj]) * s + a.b[jj];
  }
}

// ---------------- prep: cast x->bf16 + x->fp8(identity) in one pass | bucket histogram | weight pack ----------------

__global__ __launch_bounds__(256) void k_prep(const float* __restrict__ x, int n4, unsigned* __restrict__ xb,
                                              unsigned* __restrict__ xq,
                                              const int* __restrict__ dst, int E,
                                              int* __restrict__ bcnt, int nbuck,
                                              int castBlocks, int histBlocks,
                                              WtpArgs a0, WtpArgs a1, WtpArgs a2, WtpArgs a3){
  __shared__ int s[NBUCK_MAX];
  int b = blockIdx.x, t = threadIdx.x;
  if (b < castBlocks){
    int i = b*256 + t;            // i over groups of 4 floats
    if (i < n4){
      float4 v = ((const float4*)x)[i];
      uint2 o; o.x = pack2(v.x, v.y); o.y = pack2(v.z, v.w);
      ((uint2*)xb)[i] = o;
      xq[i] = pk_fp8x4(v.x, v.y, v.z, v.w);    // identity channel order
    }
    return;
  }
  b -= castBlocks;
  if (b < histBlocks){
    for (int i=t;i<nbuck;i+=256) s[i] = 0;
    __syncthreads();
    constexpr int EPT = 16;
    int e0 = b*256*EPT;
    #pragma unroll
    for (int i=0;i<EPT;i++){
      int e = e0 + i*256 + t;
      if (e < E) atomicAdd(&s[dst[e] >> 7], 1);
    }
    __syncthreads();
    for (int i=t;i<nbuck;i+=256){
      int c = s[i];
      if (c > 0) atomicAdd(&bcnt[i], c);
    }
    return;
  }
  b -= histBlocks;
  if (b < a0.nblk){ wtp_one(a0, b*256 + t); return; }
  b -= a0.nblk;
  if (b < a1.nblk){ wtp_one(a1, b*256 + t); return; }
  b -= a1.nblk;
  if (b < a2.nblk){ wtp_one(a2, b*256 + t); return; }
  b -= a2.nblk;
  wtp_one(a3, b*256 + t);
}

// Pass A: bin edges into 128-node buckets; bucket region in ebuf == final csr region.
// Per-block LDS scan of bcnt replaces a separate scan kernel.
// Packed entry: (local_dst << 16) | src  (requires N <= 65536)
__global__ __launch_bounds__(256) void k_bucketA(const int* __restrict__ src, const int* __restrict__ dst,
                                                 int E, const int* __restrict__ bcnt,
                                                 int* __restrict__ bcur, unsigned* __restrict__ ebuf, int nbuck){
  __shared__ int scnt[NBUCK_MAX];
  __shared__ int sbase[NBUCK_MAX];
  __shared__ int sboff[NBUCK_MAX];
  __shared__ int ss[256];
  int t = threadIdx.x;
  // exclusive scan of bcnt -> sboff
  {
    int a0 = (2*t   < nbuck) ? bcnt[2*t]   : 0;
    int a1 = (2*t+1 < nbuck) ? bcnt[2*t+1] : 0;
    ss[t] = a0 + a1; __syncthreads();
    for (int d=1; d<256; d<<=1){
      int u = (t>=d) ? ss[t-d] : 0;
      __syncthreads();
      ss[t] += u;
      __syncthreads();
    }
    int excl = ss[t] - (a0 + a1);
    if (2*t   < nbuck) sboff[2*t]   = excl;
    if (2*t+1 < nbuck) sboff[2*t+1] = excl + a0;
  }
  for (int i=t;i<nbuck;i+=256) scnt[i] = 0;
  __syncthreads();
  constexpr int EPT = 16;
  int e0 = blockIdx.x*256*EPT;
  int b[EPT]; unsigned pk[EPT];
  #pragma unroll
  for (int i=0;i<EPT;i++){
    int e = e0 + i*256 + t;
    if (e < E){
      int d = dst[e];
      b[i] = d >> 7;
      pk[i] = ((unsigned)(d & 127) << 16) | (unsigned)src[e];
      atomicAdd(&scnt[b[i]], 1);
    } else b[i] = -1;
  }
  __syncthreads();
  for (int i=t;i<nbuck;i+=256){
    int c = scnt[i];
    sbase[i] = (c > 0) ? atomicAdd(&bcur[i], c) : 0;
    scnt[i] = 0;
  }
  __syncthreads();
  #pragma unroll
  for (int i=0;i<EPT;i++){
    if (b[i] >= 0){
      int p = atomicAdd(&scnt[b[i]], 1);
      ebuf[(size_t)sboff[b[i]] + sbase[b[i]] + p] = pk[i];
    }
  }
}

// Pass B: one block per bucket; degree count, DEGREE-DESCENDING bitonic sort of the 128 nodes,
// rank-ordered csr layout + offR (rank-indexed) + nodemap (rank -> node id).
__global__ __launch_bounds__(256) void k_bucketB(const unsigned* __restrict__ ebuf, const int* __restrict__ bcnt,
                                                 int nbuck, int E, int N,
                                                 int* __restrict__ offR, int* __restrict__ csr,
                                                 int* __restrict__ nodemap){
  __shared__ int sEx[NBUCK_MAX];
  __shared__ int ss[256];
  __shared__ int sdeg[128];
  __shared__ int sabs[129];
  __shared__ int cur[128];
  __shared__ unsigned skey[128];
  __shared__ int rof[128];
  int b = blockIdx.x, t = threadIdx.x;
  // exclusive scan of bcnt -> sEx
  {
    int a0 = (2*t   < nbuck) ? bcnt[2*t]   : 0;
    int a1 = (2*t+1 < nbuck) ? bcnt[2*t+1] : 0;
    ss[t] = a0 + a1; __syncthreads();
    for (int d=1; d<256; d<<=1){
      int u = (t>=d) ? ss[t-d] : 0;
      __syncthreads();
      ss[t] += u;
      __syncthreads();
    }
    int excl = ss[t] - (a0 + a1);
    if (2*t   < nbuck) sEx[2*t]   = excl;
    if (2*t+1 < nbuck) sEx[2*t+1] = excl + a0;
  }
  if (t < 128){ sdeg[t] = 0; cur[t] = 0; }
  __syncthreads();
  int e0 = sEx[b];
  int e1 = (b+1 < nbuck) ? sEx[b+1] : E;
  for (int e = e0 + t; e < e1; e += 256)
    atomicAdd(&sdeg[ebuf[e] >> 16], 1);
  __syncthreads();
  // key = (deg<<7) | (127-lid): descending sort => high degree first; ties favor small lid
  if (t < 128) skey[t] = ((unsigned)sdeg[t] << 7) | (unsigned)(127 - t);
  __syncthreads();
  #pragma unroll
  for (int k=2; k<=128; k<<=1){
    #pragma unroll
    for (int j=k>>1; j>0; j>>=1){
      if (t < 128){
        int p = t ^ j;
        if (p > t){
          unsigned x = skey[t], y = skey[p];
          bool swap = ((t & k) == 0) ? (x < y) : (x > y);
          if (swap){ skey[t] = y; skey[p] = x; }
        }
      }
      __syncthreads();
    }
  }
  if (t < 128){
    int lid = 127 - (int)(skey[t] & 127u);
    rof[lid] = t;                       // rank of local id
    sdeg[t] = (int)(skey[t] >> 7);      // sdeg now rank-indexed (sorted degrees)
  }
  __syncthreads();
  // scan sorted degrees -> per-rank absolute starts
  for (int d=1; d<128; d<<=1){
    int u = (t < 128 && t >= d) ? sdeg[t-d] : 0;
    __syncthreads();
    if (t < 128) sdeg[t] += u;
    __syncthreads();
  }
  if (t == 0) sabs[0] = e0;
  if (t < 128) sabs[t+1] = e0 + sdeg[t];
  __syncthreads();
  int n0 = b << 7, n1 = min(n0 + 128, N);
  int cnt = n1 - n0;
  if (t <= cnt) offR[n0 + t] = sabs[t];
  if (t < cnt)  nodemap[n0 + t] = n0 + (127 - (int)(skey[t] & 127u));
  for (int e = e0 + t; e < e1; e += 256){
    unsigned pr = ebuf[e];
    int ln = (int)(pr >> 16);
    int p = atomicAdd(&cur[ln], 1);
    csr[sabs[rof[ln]] + p] = (int)(pr & 0xffffu);
  }
}

// ---------------- FUSED layer kernel: per-bucket mean gather (fp8) -> LDS + K=256 MFMA GEMM + BN/ReLU ----------------
// A = [mean | h] (K=256): mean half from LDS tile (padded stride 136 shorts, conflict-free ds_read_b128),
// h half from global rows. B fragments read directly from global (L2-resident 64KB, shared by all blocks).
// !YL: writes h bf16 + fp8(perm) copy. YL: also yl = h2 @ Wl2^T via LDS restage, written fp8(perm2).

template<bool YL>
__global__ __launch_bounds__(256, 2) void k_fuse(
    const uint4* __restrict__ hq4, const int* __restrict__ offR, const int* __restrict__ csr,
    const int* __restrict__ nodemap,
    const unsigned short* __restrict__ Ag, const unsigned short* __restrict__ Bpk,
    const float* __restrict__ sc, const float* __restrict__ sh,
    const unsigned short* __restrict__ BpkL,
    unsigned short* __restrict__ outh, unsigned* __restrict__ outq,
    unsigned* __restrict__ outyl, int n){
  __shared__ uint4 Ms4[128*17];     // 34816 B: 128 rows x 136 shorts (padded; row = 17 uint4)
  __shared__ uint4 sBL4[1024];      // 16384 B: csr window (gather) -> BpkL stage (yl phase)
  __shared__ int sw[2];
  unsigned short* Ms = (unsigned short*)Ms4;
  int* scsr = (int*)sBL4;
  int t = threadIdx.x;
  int mb = blockIdx.x*128;
  if (t < 2) sw[t] = offR[min(mb + t*128, n)];
  __syncthreads();
  int e0b = sw[0];
  int span = sw[1] - e0b;
  for (int i = t; i < span && i < FUSE_CAP; i += 256) scsr[i] = csr[e0b + i];
  __syncthreads();

  int lane = t & 63, w = t >> 6;
  int sl = lane & 7;

  // ---- gather phase: rank slots, 8 lanes x uint4 per node, 4 node-iters per 8-lane group ----
  #pragma unroll
  for (int it=0; it<4; it++){
    int rk = w*32 + it*8 + (lane >> 3);
    int idx = mb + rk;
    bool valid = idx < n;
    int s0 = valid ? offR[idx]   : 0;
    int s1 = valid ? offR[idx+1] : 0;
    int ln = valid ? (nodemap[idx] - mb) : rk;
    f32x2 b0={0,0},b1={0,0},b2={0,0},b3={0,0},b4={0,0},b5={0,0},b6={0,0},b7={0,0};
    int e = s0;
    for (; e + 8 <= s1; e += 8){
      int le = e - e0b;
      int i0,i1,i2,i3,i4,i5,i6,i7;
      if (le + 8 <= FUSE_CAP){
        i0 = scsr[le];   i1 = scsr[le+1]; i2 = scsr[le+2]; i3 = scsr[le+3];
        i4 = scsr[le+4]; i5 = scsr[le+5]; i6 = scsr[le+6]; i7 = scsr[le+7];
      } else {
        i0 = csr[e];   i1 = csr[e+1]; i2 = csr[e+2]; i3 = csr[e+3];
        i4 = csr[e+4]; i5 = csr[e+5]; i6 = csr[e+6]; i7 = csr[e+7];
      }
      uint4 v0 = hq4[(size_t)i0*8 + sl];
      uint4 v1 = hq4[(size_t)i1*8 + sl];
      uint4 v2 = hq4[(size_t)i2*8 + sl];
      uint4 v3 = hq4[(size_t)i3*8 + sl];
      uint4 v4 = hq4[(size_t)i4*8 + sl];
      uint4 v5 = hq4[(size_t)i5*8 + sl];
      uint4 v6 = hq4[(size_t)i6*8 + sl];
      uint4 v7 = hq4[(size_t)i7*8 + sl];
      ACCP16(v0); ACCP16(v1); ACCP16(v2); ACCP16(v3);
      ACCP16(v4); ACCP16(v5); ACCP16(v6); ACCP16(v7);
    }
    for (; e + 4 <= s1; e += 4){
      int le = e - e0b;
      int i0,i1,i2,i3;
      if (le + 4 <= FUSE_CAP){
        i0 = scsr[le]; i1 = scsr[le+1]; i2 = scsr[le+2]; i3 = scsr[le+3];
      } else {
        i0 = csr[e]; i1 = csr[e+1]; i2 = csr[e+2]; i3 = csr[e+3];
      }
      uint4 v0 = hq4[(size_t)i0*8 + sl];
      uint4 v1 = hq4[(size_t)i1*8 + sl];
      uint4 v2 = hq4[(size_t)i2*8 + sl];
      uint4 v3 = hq4[(size_t)i3*8 + sl];
      ACCP16(v0); ACCP16(v1); ACCP16(v2); ACCP16(v3);
    }
    for (; e < s1; e++){
      int le = e - e0b;
      int ii = (le < FUSE_CAP) ? scsr[le] : csr[e];
      uint4 v = hq4[(size_t)ii*8 + sl];
      ACCP16(v);
    }
    int d = s1 - s0;
    float inv = 1.0f / (float)(d > 0 ? d : 1);
    uint4 o0, o1;
    o0.x = pack2(b0.x*inv, b0.y*inv);  o0.y = pack2(b1.x*inv, b1.y*inv);
    o0.z = pack2(b2.x*inv, b2.y*inv);  o0.w = pack2(b3.x*inv, b3.y*inv);
    o1.x = pack2(b4.x*inv, b4.y*inv);  o1.y = pack2(b5.x*inv, b5.y*inv);
    o1.z = pack2(b6.x*inv, b6.y*inv);  o1.w = pack2(b7.x*inv, b7.y*inv);
    Ms4[ln*17 + sl*2]     = o0;
    Ms4[ln*17 + sl*2 + 1] = o1;
  }
  __syncthreads();

  // ---- GEMM phase: C = [mean | Ag] @ B (K=256), BN + ReLU ----
  int quad = lane >> 4, c = lane & 15;
  int woff = w*32;
  int r0 = mb + woff + c;
  int r1 = r0 + 16;

  f32x4 acc[2][8];
  #pragma unroll
  for (int mt=0;mt<2;mt++)
    #pragma unroll
    for (int nt=0;nt<8;nt++) acc[mt][nt] = (f32x4){0.f,0.f,0.f,0.f};

  #pragma unroll
  for (int kk=0; kk<8; kk++){
    int ka = (kk & 3)*32 + quad*8;
    short8 a0, a1;
    if (kk < 4){
      a0 = *(const short8*)&Ms[(woff + c)*136 + ka];
      a1 = *(const short8*)&Ms[(woff + c + 16)*136 + ka];
    } else {
      a0 = (short8){0,0,0,0,0,0,0,0}; a1 = (short8){0,0,0,0,0,0,0,0};
      if (r0 < n) a0 = *(const short8*)(Ag + (size_t)r0*128 + ka);
      if (r1 < n) a1 = *(const short8*)(Ag + (size_t)r1*128 + ka);
    }
    #pragma unroll
    for (int nt=0; nt<8; nt++){
      short8 b = *(const short8*)(Bpk + (size_t)((kk*8 + nt)*64 + lane)*8);
      acc[0][nt] = __builtin_amdgcn_mfma_f32_16x16x32_bf16(a0, b, acc[0][nt], 0, 0, 0);
      acc[1][nt] = __builtin_amdgcn_mfma_f32_16x16x32_bf16(a1, b, acc[1][nt], 0, 0, 0);
    }
  }

  float scv[8], shv[8];
  #pragma unroll
  for (int nt=0;nt<8;nt++){ scv[nt] = sc[nt*16 + c]; shv[nt] = sh[nt*16 + c]; }

  if constexpr (YL) __syncthreads();   // all A-reads of Ms done before epilogue overwrites it

  #pragma unroll
  for (int mt=0; mt<2; mt++){
    #pragma unroll
    for (int r=0;r<4;r++){
      int lrow = woff + mt*16 + quad*4 + r;
      int row = mb + lrow;
      if (row < n){
        float u[8];
        #pragma unroll
        for (int nt=0;nt<8;nt++){
          float uu = acc[mt][nt][r]*scv[nt] + shv[nt];
          u[nt] = fmaxf(uu, 0.f);
          outh[(size_t)row*128 + nt*16 + c] = f2bf(u[nt]);
        }
        if constexpr (!YL){
          // fp8(perm) copy for the next layer's gather: bytes row*128 + c*8 + j hold channel j*16+c
          uint2 q;
          q.x = pk_fp8x4(u[0], u[1], u[2], u[3]);
          q.y = pk_fp8x4(u[4], u[5], u[6], u[7]);
          ((uint2*)outq)[(size_t)row*16 + c] = q;
        } else {
          // write BN+ReLU'd h2 into Ms (natural channel positions) for the yl mini-GEMM
          #pragma unroll
          for (int nt=0;nt<8;nt++) Ms[lrow*136 + nt*16 + c] = f2bf(u[nt]);
        }
      } else if constexpr (YL) {
        #pragma unroll
        for (int nt=0;nt<8;nt++) Ms[lrow*136 + nt*16 + c] = 0;
      }
    }
  }

  if constexpr (YL){
    // stage BpkL (128x64 bf16 = 1024 uint4) into the csr-window region
    {
      const uint4* sL = (const uint4*)BpkL;
      #pragma unroll
      for (int i=0;i<4;i++) sBL4[i*256 + t] = sL[i*256 + t];
    }
    __syncthreads();
    unsigned short* BsL = (unsigned short*)sBL4;
    f32x4 acc2[2][4];
    #pragma unroll
    for (int mt=0;mt<2;mt++)
      #pragma unroll
      for (int nt=0;nt<4;nt++) acc2[mt][nt] = (f32x4){0.f,0.f,0.f,0.f};
    int r0l = woff + c, r1l = r0l + 16;
    #pragma unroll
    for (int kk=0; kk<4; kk++){
      int ka = kk*32 + quad*8;
      short8 a0 = *(const short8*)&Ms[r0l*136 + ka];
      short8 a1 = *(const short8*)&Ms[r1l*136 + ka];
      #pragma unroll
      for (int nt=0; nt<4; nt++){
        short8 b = *(const short8*)&BsL[(size_t)((kk*4 + nt)*64 + lane)*8];
        acc2[0][nt] = __builtin_amdgcn_mfma_f32_16x16x32_bf16(a0, b, acc2[0][nt], 0, 0, 0);
        acc2[1][nt] = __builtin_amdgcn_mfma_f32_16x16x32_bf16(a1, b, acc2[1][nt], 0, 0, 0);
      }
    }
    #pragma unroll
    for (int mt=0; mt<2; mt++){
      #pragma unroll
      for (int r=0;r<4;r++){
        int row = mb + woff + mt*16 + quad*4 + r;
        if (row < n){
          // fp8(perm2): byte row*64 + c*4 + nt holds channel nt*16+c
          unsigned q  = pk_fp8x4(acc2[0][0][r], acc2[0][1][r], acc2[0][2][r], acc2[0][3][r]);
          unsigned q1 = pk_fp8x4(acc2[1][0][r], acc2[1][1][r], acc2[1][2][r], acc2[1][3][r]);
          outyl[(size_t)row*16 + c] = (mt == 0) ? q : q1;
        }
      }
    }
  }
}

// ---------------- fused layer-3: mean-yl gather (64-dim fp8, rank slots) + GEMM (h_b@Wr2^T) + BN + L2norm ----------------

__global__ __launch_bounds__(256, 2) void k_aggf(
    const uint4* __restrict__ ylq4, const int* __restrict__ offR, const int* __restrict__ csr,
    const int* __restrict__ nodemap,
    const unsigned short* __restrict__ A0, const unsigned short* __restrict__ BpkR,
    const float* __restrict__ sc, const float* __restrict__ sh,
    float* __restrict__ outf, int n){
  __shared__ unsigned short Ms[128*64];   // 16 KB mean-yl tile (bf16, perm2 positions)
  __shared__ unsigned short Bs[128*64];   // 16 KB BpkR
  __shared__ int scsr[AGGF_CAP];          // 12 KB staged csr window
  __shared__ int sw[2];
  int t = threadIdx.x;
  int mb = blockIdx.x*128;
  if (t < 2) sw[t] = offR[min(mb + t*128, n)];
  {
    const uint4* s = (const uint4*)BpkR;
    uint4* d = (uint4*)Bs;
    #pragma unroll
    for (int i=0;i<4;i++) d[i*256 + t] = s[i*256 + t];
  }
  __syncthreads();
  int e0b = sw[0];
  int span = sw[1] - e0b;
  for (int i = t; i < span && i < AGGF_CAP; i += 256) scsr[i] = csr[e0b + i];
  __syncthreads();

  int lane = t & 63, w = t >> 6;
  int sl4 = lane & 3;

  // gather phase: rank slots; wave w covers ranks [w*32, w*32+32), 16 at a time, 4 lanes x uint4 each
  #pragma unroll
  for (int it=0; it<2; it++){
    int rk = w*32 + it*16 + (lane >> 2);
    int idx = mb + rk;
    bool valid = idx < n;
    int s0 = valid ? offR[idx]   : 0;
    int s1 = valid ? offR[idx+1] : 0;
    int ln = valid ? (nodemap[idx] - mb) : rk;
    f32x2 b0={0,0},b1={0,0},b2={0,0},b3={0,0},b4={0,0},b5={0,0},b6={0,0},b7={0,0};
    int e = s0;
    for (; e + 8 <= s1; e += 8){
      int le = e - e0b;
      int i0,i1,i2,i3,i4,i5,i6,i7;
      if (le + 8 <= AGGF_CAP){
        i0 = scsr[le];   i1 = scsr[le+1]; i2 = scsr[le+2]; i3 = scsr[le+3];
        i4 = scsr[le+4]; i5 = scsr[le+5]; i6 = scsr[le+6]; i7 = scsr[le+7];
      } else {
        i0 = csr[e];   i1 = csr[e+1]; i2 = csr[e+2]; i3 = csr[e+3];
        i4 = csr[e+4]; i5 = csr[e+5]; i6 = csr[e+6]; i7 = csr[e+7];
      }
      uint4 v0 = ylq4[(size_t)i0*4 + sl4];
      uint4 v1 = ylq4[(size_t)i1*4 + sl4];
      uint4 v2 = ylq4[(size_t)i2*4 + sl4];
      uint4 v3 = ylq4[(size_t)i3*4 + sl4];
      uint4 v4 = ylq4[(size_t)i4*4 + sl4];
      uint4 v5 = ylq4[(size_t)i5*4 + sl4];
      uint4 v6 = ylq4[(size_t)i6*4 + sl4];
      uint4 v7 = ylq4[(size_t)i7*4 + sl4];
      ACCP16(v0); ACCP16(v1); ACCP16(v2); ACCP16(v3);
      ACCP16(v4); ACCP16(v5); ACCP16(v6); ACCP16(v7);
    }
    for (; e + 4 <= s1; e += 4){
      int le = e - e0b;
      int i0,i1,i2,i3;
      if (le + 4 <= AGGF_CAP){
        i0 = scsr[le]; i1 = scsr[le+1]; i2 = scsr[le+2]; i3 = scsr[le+3];
      } else {
        i0 = csr[e]; i1 = csr[e+1]; i2 = csr[e+2]; i3 = csr[e+3];
      }
      uint4 v0 = ylq4[(size_t)i0*4 + sl4];
      uint4 v1 = ylq4[(size_t)i1*4 + sl4];
      uint4 v2 = ylq4[(size_t)i2*4 + sl4];
      uint4 v3 = ylq4[(size_t)i3*4 + sl4];
      ACCP16(v0); ACCP16(v1); ACCP16(v2); ACCP16(v3);
    }
    for (; e < s1; e++){
      int le = e - e0b;
      int ii = (le < AGGF_CAP) ? scsr[le] : csr[e];
      uint4 v = ylq4[(size_t)ii*4 + sl4];
      ACCP16(v);
    }
    int d = s1 - s0;
    float inv = 1.0f / (float)(d > 0 ? d : 1);
    uint4 o0, o1;
    o0.x = pack2(b0.x*inv, b0.y*inv);  o0.y = pack2(b1.x*inv, b1.y*inv);
    o0.z = pack2(b2.x*inv, b2.y*inv);  o0.w = pack2(b3.x*inv, b3.y*inv);
    o1.x = pack2(b4.x*inv, b4.y*inv);  o1.y = pack2(b5.x*inv, b5.y*inv);
    o1.z = pack2(b6.x*inv, b6.y*inv);  o1.w = pack2(b7.x*inv, b7.y*inv);
    ((uint4*)Ms)[ln*8 + sl4*2]     = o0;
    ((uint4*)Ms)[ln*8 + sl4*2 + 1] = o1;
  }
  __syncthreads();

  // GEMM phase: C = h_b @ Wr2^T (K=128), + mean-yl, BN, L2-normalize
  int quad = lane >> 4, c = lane & 15;
  int woff = w*32;
  int r0 = mb + woff + c;
  int r1 = r0 + 16;
  f32x4 acc[2][4];
  #pragma unroll
  for (int mt=0;mt<2;mt++)
    #pragma unroll
    for (int nt=0;nt<4;nt++) acc[mt][nt] = (f32x4){0.f,0.f,0.f,0.f};
  #pragma unroll
  for (int kk=0; kk<4; kk++){
    int ka = kk*32 + quad*8;
    short8 a0 = {0,0,0,0,0,0,0,0}, a1 = {0,0,0,0,0,0,0,0};
    if (r0 < n) a0 = *(const short8*)(A0 + (size_t)r0*128 + ka);
    if (r1 < n) a1 = *(const short8*)(A0 + (size_t)r1*128 + ka);
    #pragma unroll
    for (int nt=0; nt<4; nt++){
      short8 b = *(const short8*)&Bs[(size_t)((kk*4 + nt)*64 + lane)*8];
      acc[0][nt] = __builtin_amdgcn_mfma_f32_16x16x32_bf16(a0, b, acc[0][nt], 0, 0, 0);
      acc[1][nt] = __builtin_amdgcn_mfma_f32_16x16x32_bf16(a1, b, acc[1][nt], 0, 0, 0);
    }
  }

  float scv[4], shv[4];
  #pragma unroll
  for (int nt=0;nt<4;nt++){ scv[nt] = sc[nt*16 + c]; shv[nt] = sh[nt*16 + c]; }

  #pragma unroll
  for (int mt=0; mt<2; mt++){
    #pragma unroll
    for (int r=0;r<4;r++){
      int lr = woff + mt*16 + quad*4 + r;
      int row = mb + lr;
      float v[4];
      float ss = 0.f;
      if (row < n){
        #pragma unroll
        for (int nt=0;nt<4;nt++){
          // Ms holds perm2 positions: channel nt*16+c lives at position c*4+nt
          float u = acc[mt][nt][r] + bf2f(Ms[lr*64 + c*4 + nt]);
          u = u*scv[nt] + shv[nt];
          v[nt] = u;
          ss += u*u;
        }
      } else {
        #pragma unroll
        for (int nt=0;nt<4;nt++) v[nt] = 0.f;
      }
      ss += __shfl_xor(ss, 1, 64);
      ss += __shfl_xor(ss, 2, 64);
      ss += __shfl_xor(ss, 4, 64);
      ss += __shfl_xor(ss, 8, 64);
      float rn = 1.0f / fmaxf(sqrtf(ss), 1e-12f);
      if (row < n){
        #pragma unroll
        for (int nt=0;nt<4;nt++) outf[(size_t)row*64 + nt*16 + c] = v[nt]*rn;
      }
    }
  }
}

// ---------------- launcher ----------------

extern "C" void kernel_launch(void* const* d_in, const int* in_sizes, int n_in,
                              void* d_out, int out_size, void* d_ws, size_t ws_size,
                              hipStream_t stream){
  const float* x = (const float*)d_in[0];
  const int* ei  = (const int*)d_in[1];
  int N = in_sizes[0] / 128;
  int E = in_sizes[1] / 2;
  const int* esrc = ei;
  const int* edst = ei + E;
  int nbuck = CDIV(N, 128);

  const float *Wl[3], *bl[3], *Wr[3], *g[3], *bb[3], *rm[3], *rv[3];
  int dout[3];
  for (int i=0;i<3;i++){
    int base = 2 + 7*i;
    Wl[i]=(const float*)d_in[base];   bl[i]=(const float*)d_in[base+1];
    Wr[i]=(const float*)d_in[base+2]; g[i] =(const float*)d_in[base+3];
    bb[i]=(const float*)d_in[base+4]; rm[i]=(const float*)d_in[base+5];
    rv[i]=(const float*)d_in[base+6];
    dout[i] = in_sizes[base] / 128;
  }

  char* p = (char*)d_ws;
  size_t o = 0;
  auto alloc = [&](size_t bytes)->void*{ void* r = p + o; o += (bytes + 255) & ~(size_t)255; return r; };
  int* bz    = (int*)alloc((size_t)2*nbuck*4);   // bcnt | bcur (one memset)
  int* bcnt  = bz;
  int* bcur  = bz + nbuck;
  int* offR  = (int*)alloc((size_t)(N+1)*4);     // rank-indexed csr offsets
  int* nodemap = (int*)alloc((size_t)N*4);       // rank slot -> node id
  int* csr   = (int*)alloc((size_t)E*4);
  unsigned* ebuf = (unsigned*)alloc((size_t)E*4);
  unsigned* xb   = (unsigned*)alloc((size_t)N*64*4);   // bf16 x (natural)
  unsigned* xq   = (unsigned*)alloc((size_t)N*128);    // fp8 x (identity order)
  unsigned* h_a  = (unsigned*)alloc((size_t)N*64*4);   // bf16 h1 (natural)
  unsigned* haq  = (unsigned*)alloc((size_t)N*128);    // fp8 h1 (perm)
  unsigned* h_b  = (unsigned*)alloc((size_t)N*64*4);   // bf16 h2 (natural)
  unsigned* ylb  = (unsigned*)alloc((size_t)N*64);     // fp8 yl (perm2)
  unsigned short* Bpk01[2];
  float* sc[3]; float* sh[3];
  for (int i=0;i<2;i++) Bpk01[i] = (unsigned short*)alloc((size_t)256*dout[i]*2);
  unsigned short* BpkL = (unsigned short*)alloc((size_t)128*dout[2]*2);
  unsigned short* BpkR = (unsigned short*)alloc((size_t)128*dout[2]*2);
  for (int i=0;i<3;i++){
    sc[i] = (float*)alloc((size_t)dout[i]*4);
    sh[i] = (float*)alloc((size_t)dout[i]*4);
  }

  hipMemsetAsync(bz, 0, (size_t)2*nbuck*4, stream);

  WtpArgs wa[4];
  wa[0] = { Wl[0], Wr[0], bl[0], g[0], bb[0], rm[0], rv[0], Bpk01[0], sc[0], sh[0], 8, dout[0], 1, CDIV(256*dout[0]+dout[0],256), 0 };
  wa[1] = { Wl[1], Wr[1], bl[1], g[1], bb[1], rm[1], rv[1], Bpk01[1], sc[1], sh[1], 8, dout[1], 1, CDIV(256*dout[1]+dout[1],256), 1 };
  wa[2] = { Wl[2], nullptr, nullptr, nullptr, nullptr, nullptr, nullptr, BpkL, nullptr, nullptr, 4, dout[2], 0, CDIV(128*dout[2],256), 0 };
  wa[3] = { Wr[2], nullptr, bl[2], g[2], bb[2], rm[2], rv[2], BpkR, sc[2], sh[2], 4, dout[2], 1, CDIV(128*dout[2]+dout[2],256), 0 };

  int castBlocks = CDIV(N*32, 256);
  int histBlocks = CDIV(E, 256*16);
  int prepBlocks = castBlocks + histBlocks + wa[0].nblk + wa[1].nblk + wa[2].nblk + wa[3].nblk;
  k_prep   <<<prepBlocks,256,0,stream>>>(x, N*32, xb, xq, edst, E, bcnt, nbuck, castBlocks, histBlocks,
                                         wa[0], wa[1], wa[2], wa[3]);
  k_bucketA<<<CDIV(E,256*16),256,0,stream>>>(esrc, edst, E, bcnt, bcur, ebuf, nbuck);
  k_bucketB<<<nbuck,256,0,stream>>>(ebuf, bcnt, nbuck, E, N, offR, csr, nodemap);

  // layer 0: fused gather(xq) + GEMM0 -> h_a (bf16) + haq (fp8 perm)
  k_fuse<false><<<nbuck,256,0,stream>>>((const uint4*)xq, offR, csr, nodemap,
                                        (const unsigned short*)xb, Bpk01[0], sc[0], sh[0], nullptr,
                                        (unsigned short*)h_a, haq, nullptr, N);
  // layer 1: fused gather(haq) + GEMM1 + yl mini-GEMM -> h_b (bf16) + ylb (fp8 perm2)
  k_fuse<true><<<nbuck,256,0,stream>>>((const uint4*)haq, offR, csr, nodemap,
                                       (const unsigned short*)h_a, Bpk01[1], sc[1], sh[1], BpkL,
                                       (unsigned short*)h_b, nullptr, ylb, N);
  // layer 2: fused mean-yl gather + final GEMM + BN + L2norm
  k_aggf<<<nbuck,256,0,stream>>>((const uint4*)ylb, offR, csr, nodemap,
                                 (const unsigned short*)h_b, BpkR, sc[2], sh[2],
                                 (float*)d_out, N);
}

// Round 5
// 236.148 us; speedup vs baseline: 1.0281x; 1.0281x over previous
//
#include <hip/hip_runtime.h>
#include <hip/hip_bf16.h>

#define CDIV(a,b) (((a)+(b)-1)/(b))
#define NBUCK_MAX 512   // buckets of 128 nodes; supports N up to 65536 (ebuf packing needs N<=65536)
#define FUSE_CAP 3072   // staged csr entries per fused block (128 nodes, mean 2048, +22 sigma)

typedef __attribute__((ext_vector_type(8))) short short8;
typedef __attribute__((ext_vector_type(4))) float f32x4;
typedef __attribute__((ext_vector_type(2))) float f32x2;

static __device__ __forceinline__ unsigned short f2bf(float f){
  union { float f; unsigned u; } v; v.f = f;
  unsigned r = v.u + 0x7fffu + ((v.u >> 16) & 1u);   // RNE
  return (unsigned short)(r >> 16);
}
static __device__ __forceinline__ unsigned pack2(float lo, float hi){
  return (unsigned)f2bf(lo) | ((unsigned)f2bf(hi) << 16);
}
static __device__ __forceinline__ float bf2f(unsigned short s){
  union { unsigned u; float f; } v; v.u = ((unsigned)s) << 16; return v.f;
}
// pack 4 f32 -> 4 fp8 e4m3 bytes (byte0=a .. byte3=d)
static __device__ __forceinline__ unsigned pk_fp8x4(float a, float b, float c, float d){
  int v = __builtin_amdgcn_cvt_pk_fp8_f32(a, b, 0, false);
  v = __builtin_amdgcn_cvt_pk_fp8_f32(c, d, v, true);
  return (unsigned)v;
}

// accumulate 16 fp8 bytes (uint4) into f32x2 accumulators b0..b7 (v_pk_add_f32 path)
#define ACCP16(v) { b0 += __builtin_amdgcn_cvt_pk_f32_fp8((int)v.x, false); \
                    b1 += __builtin_amdgcn_cvt_pk_f32_fp8((int)v.x, true);  \
                    b2 += __builtin_amdgcn_cvt_pk_f32_fp8((int)v.y, false); \
                    b3 += __builtin_amdgcn_cvt_pk_f32_fp8((int)v.y, true);  \
                    b4 += __builtin_amdgcn_cvt_pk_f32_fp8((int)v.z, false); \
                    b5 += __builtin_amdgcn_cvt_pk_f32_fp8((int)v.z, true);  \
                    b6 += __builtin_amdgcn_cvt_pk_f32_fp8((int)v.w, false); \
                    b7 += __builtin_amdgcn_cvt_pk_f32_fp8((int)v.w, true); }

// ---------------- weight pack args ----------------
// perm: first-128 K positions hold channel pi(k) = (k&7)*16 + (k>>3) (matches gemm-epilogue fp8 row layout)

struct WtpArgs {
  const float *W0, *W1, *bl, *g, *b, *rm, *rv;
  unsigned short* Bpk; float *sc; float *sh;
  int kblk, dout, do_bn, nblk, perm;
};

static __device__ __forceinline__ void wtp_one(const WtpArgs& a, int idx){
  int NB16 = a.kblk*32*a.dout;
  if (idx < NB16){
    int j = idx & 7, lane = (idx >> 3) & 63, rest = idx >> 9;
    int NT = a.dout >> 4;
    int nt = rest % NT, kk = rest / NT;
    int nn = nt*16 + (lane & 15);
    int k  = kk*32 + ((lane >> 4) * 8) + j;
    float v;
    if (k < 128){
      int kc = a.perm ? (((k & 7) << 4) | (k >> 3)) : k;
      v = a.W0[nn*128 + kc];
    } else {
      v = a.W1[nn*128 + (k - 128)];
    }
    a.Bpk[idx] = f2bf(v);
  } else if (a.do_bn && idx < NB16 + a.dout){
    int jj = idx - NB16;
    float s = a.g[jj] * rsqrtf(a.rv[jj] + 1e-5f);
    a.sc[jj] = s;
    a.sh[jj] = (a.bl[jj] - a.rm[jj]) * s + a.b[jj];
  }
}

// ---------------- prep: cast x->bf16 + x->fp8(identity) in one pass | bucket histogram | weight pack ----------------

__global__ __launch_bounds__(256) void k_prep(const float* __restrict__ x, int n4, unsigned* __restrict__ xb,
                                              unsigned* __restrict__ xq,
                                              const int* __restrict__ dst, int E,
                                              int* __restrict__ bcnt, int nbuck,
                                              int castBlocks, int histBlocks,
                                              WtpArgs a0, WtpArgs a1, WtpArgs a2, WtpArgs a3){
  __shared__ int s[NBUCK_MAX];
  int b = blockIdx.x, t = threadIdx.x;
  if (b < castBlocks){
    int i = b*256 + t;            // i over groups of 4 floats
    if (i < n4){
      float4 v = ((const float4*)x)[i];
      uint2 o; o.x = pack2(v.x, v.y); o.y = pack2(v.z, v.w);
      ((uint2*)xb)[i] = o;
      xq[i] = pk_fp8x4(v.x, v.y, v.z, v.w);    // identity channel order
    }
    return;
  }
  b -= castBlocks;
  if (b < histBlocks){
    for (int i=t;i<nbuck;i+=256) s[i] = 0;
    __syncthreads();
    constexpr int EPT = 16;
    int e0 = b*256*EPT;
    #pragma unroll
    for (int i=0;i<EPT;i++){
      int e = e0 + i*256 + t;
      if (e < E) atomicAdd(&s[dst[e] >> 7], 1);
    }
    __syncthreads();
    for (int i=t;i<nbuck;i+=256){
      int c = s[i];
      if (c > 0) atomicAdd(&bcnt[i], c);
    }
    return;
  }
  b -= histBlocks;
  if (b < a0.nblk){ wtp_one(a0, b*256 + t); return; }
  b -= a0.nblk;
  if (b < a1.nblk){ wtp_one(a1, b*256 + t); return; }
  b -= a1.nblk;
  if (b < a2.nblk){ wtp_one(a2, b*256 + t); return; }
  b -= a2.nblk;
  wtp_one(a3, b*256 + t);
}

// Pass A: bin edges into 128-node buckets; bucket region in ebuf == final csr region.
// Per-block LDS scan of bcnt. Packed entry: (local_dst << 16) | src  (requires N <= 65536)
__global__ __launch_bounds__(256) void k_bucketA(const int* __restrict__ src, const int* __restrict__ dst,
                                                 int E, const int* __restrict__ bcnt,
                                                 int* __restrict__ bcur, unsigned* __restrict__ ebuf, int nbuck){
  __shared__ int scnt[NBUCK_MAX];
  __shared__ int sbase[NBUCK_MAX];
  __shared__ int sboff[NBUCK_MAX];
  __shared__ int ss[256];
  int t = threadIdx.x;
  // exclusive scan of bcnt -> sboff
  {
    int a0 = (2*t   < nbuck) ? bcnt[2*t]   : 0;
    int a1 = (2*t+1 < nbuck) ? bcnt[2*t+1] : 0;
    ss[t] = a0 + a1; __syncthreads();
    for (int d=1; d<256; d<<=1){
      int u = (t>=d) ? ss[t-d] : 0;
      __syncthreads();
      ss[t] += u;
      __syncthreads();
    }
    int excl = ss[t] - (a0 + a1);
    if (2*t   < nbuck) sboff[2*t]   = excl;
    if (2*t+1 < nbuck) sboff[2*t+1] = excl + a0;
  }
  for (int i=t;i<nbuck;i+=256) scnt[i] = 0;
  __syncthreads();
  constexpr int EPT = 16;
  int e0 = blockIdx.x*256*EPT;
  int b[EPT]; unsigned pk[EPT];
  #pragma unroll
  for (int i=0;i<EPT;i++){
    int e = e0 + i*256 + t;
    if (e < E){
      int d = dst[e];
      b[i] = d >> 7;
      pk[i] = ((unsigned)(d & 127) << 16) | (unsigned)src[e];
      atomicAdd(&scnt[b[i]], 1);
    } else b[i] = -1;
  }
  __syncthreads();
  for (int i=t;i<nbuck;i+=256){
    int c = scnt[i];
    sbase[i] = (c > 0) ? atomicAdd(&bcur[i], c) : 0;
    scnt[i] = 0;
  }
  __syncthreads();
  #pragma unroll
  for (int i=0;i<EPT;i++){
    if (b[i] >= 0){
      int p = atomicAdd(&scnt[b[i]], 1);
      ebuf[(size_t)sboff[b[i]] + sbase[b[i]] + p] = pk[i];
    }
  }
}

// ---------------- k_bfuse: bucketB + fused layer-0 in one kernel ----------------
// Per bucket: build local CSR in LDS from ebuf (hist+scan+scatter), write off/csr global (coalesced),
// then gather mean(x fp8) from the LDS csr -> Ms tile, then K=256 MFMA GEMM + BN/ReLU -> h_a + haq.

__global__ __launch_bounds__(256, 3) void k_bfuse(
    const unsigned* __restrict__ ebuf, const int* __restrict__ bcnt, int nbuck, int E, int N,
    int* __restrict__ off, int* __restrict__ csr,
    const uint4* __restrict__ xq4, const unsigned short* __restrict__ Ag,
    const unsigned short* __restrict__ Bpk, const float* __restrict__ sc, const float* __restrict__ sh,
    unsigned short* __restrict__ outh, unsigned* __restrict__ outq){
  __shared__ uint4 Ms4[128*17];     // 34816 B mean tile (first 1.6KB reused as sdeg/sabs/cur during csr build)
  __shared__ int scsr[FUSE_CAP];    // 12288 B local csr
  __shared__ int sEx[NBUCK_MAX];    // 2048 B scan of bcnt
  __shared__ int ss[256];           // 1024 B
  unsigned short* Ms = (unsigned short*)Ms4;
  int* sdeg = (int*)Ms4;            // [128]
  int* sabs = sdeg + 128;           // [129] local offsets
  int* cur  = sabs + 129;           // [128]
  int b = blockIdx.x, t = threadIdx.x;
  // exclusive scan of bcnt -> sEx
  {
    int a0 = (2*t   < nbuck) ? bcnt[2*t]   : 0;
    int a1 = (2*t+1 < nbuck) ? bcnt[2*t+1] : 0;
    ss[t] = a0 + a1; __syncthreads();
    for (int d=1; d<256; d<<=1){
      int u = (t>=d) ? ss[t-d] : 0;
      __syncthreads();
      ss[t] += u;
      __syncthreads();
    }
    int excl = ss[t] - (a0 + a1);
    if (2*t   < nbuck) sEx[2*t]   = excl;
    if (2*t+1 < nbuck) sEx[2*t+1] = excl + a0;
  }
  if (t < 128){ sdeg[t] = 0; cur[t] = 0; }
  __syncthreads();
  int e0 = sEx[b];
  int e1 = (b+1 < nbuck) ? sEx[b+1] : E;
  int span = e1 - e0;
  bool fits = span <= FUSE_CAP;
  for (int e = e0 + t; e < e1; e += 256)
    atomicAdd(&sdeg[ebuf[e] >> 16], 1);
  __syncthreads();
  // scan degrees -> local starts sabs[0..128]
  for (int d=1; d<128; d<<=1){
    int u = (t < 128 && t >= d) ? sdeg[t-d] : 0;
    __syncthreads();
    if (t < 128) sdeg[t] += u;
    __syncthreads();
  }
  if (t == 0) sabs[0] = 0;
  if (t < 128) sabs[t+1] = sdeg[t];
  __syncthreads();
  int n0 = b << 7, n1 = min(n0 + 128, N);
  int cnt = n1 - n0;
  if (t <= cnt) off[n0 + t] = e0 + sabs[t];
  // stash this thread's gather ranges before Ms region is reused
  int lane = t & 63, w = t >> 6, sl = lane & 7;
  int gs0[4], gs1[4];
  #pragma unroll
  for (int it=0; it<4; it++){
    int rk = w*32 + it*8 + (lane >> 3);
    gs0[it] = sabs[rk];
    gs1[it] = sabs[rk+1];
  }
  // scatter edges into local csr (LDS if fits, else global)
  for (int e = e0 + t; e < e1; e += 256){
    unsigned pr = ebuf[e];
    int ln = (int)(pr >> 16);
    int p = atomicAdd(&cur[ln], 1);
    int loc = sabs[ln] + p;
    int sv = (int)(pr & 0xffffu);
    if (fits) scsr[loc] = sv;
    else      csr[e0 + loc] = sv;
  }
  __syncthreads();
  if (fits){
    // coalesced global csr write for layers 1-2 (no barrier needed: gather only reads scsr)
    for (int i = t; i < span; i += 256) csr[e0 + i] = scsr[i];
  } else {
    // stage what fits (fallback path; statistically never taken)
    for (int i = t; i < FUSE_CAP; i += 256) scsr[i] = csr[e0 + i];
    __syncthreads();
  }

  // ---- gather phase: local offsets; 8 lanes x uint4 per node ----
  #pragma unroll
  for (int it=0; it<4; it++){
    int rk = w*32 + it*8 + (lane >> 3);
    int s0 = gs0[it], s1 = gs1[it];
    f32x2 b0={0,0},b1={0,0},b2={0,0},b3={0,0},b4={0,0},b5={0,0},b6={0,0},b7={0,0};
    int e = s0;
    for (; e + 8 <= s1; e += 8){
      int i0,i1,i2,i3,i4,i5,i6,i7;
      if (e + 8 <= FUSE_CAP){
        i0 = scsr[e];   i1 = scsr[e+1]; i2 = scsr[e+2]; i3 = scsr[e+3];
        i4 = scsr[e+4]; i5 = scsr[e+5]; i6 = scsr[e+6]; i7 = scsr[e+7];
      } else {
        i0 = csr[e0+e];   i1 = csr[e0+e+1]; i2 = csr[e0+e+2]; i3 = csr[e0+e+3];
        i4 = csr[e0+e+4]; i5 = csr[e0+e+5]; i6 = csr[e0+e+6]; i7 = csr[e0+e+7];
      }
      uint4 v0 = xq4[(size_t)i0*8 + sl];
      uint4 v1 = xq4[(size_t)i1*8 + sl];
      uint4 v2 = xq4[(size_t)i2*8 + sl];
      uint4 v3 = xq4[(size_t)i3*8 + sl];
      uint4 v4 = xq4[(size_t)i4*8 + sl];
      uint4 v5 = xq4[(size_t)i5*8 + sl];
      uint4 v6 = xq4[(size_t)i6*8 + sl];
      uint4 v7 = xq4[(size_t)i7*8 + sl];
      ACCP16(v0); ACCP16(v1); ACCP16(v2); ACCP16(v3);
      ACCP16(v4); ACCP16(v5); ACCP16(v6); ACCP16(v7);
    }
    for (; e + 4 <= s1; e += 4){
      int i0,i1,i2,i3;
      if (e + 4 <= FUSE_CAP){
        i0 = scsr[e]; i1 = scsr[e+1]; i2 = scsr[e+2]; i3 = scsr[e+3];
      } else {
        i0 = csr[e0+e]; i1 = csr[e0+e+1]; i2 = csr[e0+e+2]; i3 = csr[e0+e+3];
      }
      uint4 v0 = xq4[(size_t)i0*8 + sl];
      uint4 v1 = xq4[(size_t)i1*8 + sl];
      uint4 v2 = xq4[(size_t)i2*8 + sl];
      uint4 v3 = xq4[(size_t)i3*8 + sl];
      ACCP16(v0); ACCP16(v1); ACCP16(v2); ACCP16(v3);
    }
    for (; e < s1; e++){
      int ii = (e < FUSE_CAP) ? scsr[e] : csr[e0+e];
      uint4 v = xq4[(size_t)ii*8 + sl];
      ACCP16(v);
    }
    int d = s1 - s0;
    float inv = 1.0f / (float)(d > 0 ? d : 1);
    uint4 o0, o1;
    o0.x = pack2(b0.x*inv, b0.y*inv);  o0.y = pack2(b1.x*inv, b1.y*inv);
    o0.z = pack2(b2.x*inv, b2.y*inv);  o0.w = pack2(b3.x*inv, b3.y*inv);
    o1.x = pack2(b4.x*inv, b4.y*inv);  o1.y = pack2(b5.x*inv, b5.y*inv);
    o1.z = pack2(b6.x*inv, b6.y*inv);  o1.w = pack2(b7.x*inv, b7.y*inv);
    Ms4[rk*17 + sl*2]     = o0;
    Ms4[rk*17 + sl*2 + 1] = o1;
  }
  __syncthreads();

  // ---- GEMM phase: C = [mean | Ag] @ B (K=256), BN + ReLU ----
  int quad = lane >> 4, c = lane & 15;
  int mb = n0, woff = w*32;
  int r0 = mb + woff + c;
  int r1 = r0 + 16;

  f32x4 acc[2][8];
  #pragma unroll
  for (int mt=0;mt<2;mt++)
    #pragma unroll
    for (int nt=0;nt<8;nt++) acc[mt][nt] = (f32x4){0.f,0.f,0.f,0.f};

  #pragma unroll
  for (int kk=0; kk<8; kk++){
    int ka = (kk & 3)*32 + quad*8;
    short8 a0, a1;
    if (kk < 4){
      a0 = *(const short8*)&Ms[(woff + c)*136 + ka];
      a1 = *(const short8*)&Ms[(woff + c + 16)*136 + ka];
    } else {
      a0 = (short8){0,0,0,0,0,0,0,0}; a1 = (short8){0,0,0,0,0,0,0,0};
      if (r0 < N) a0 = *(const short8*)(Ag + (size_t)r0*128 + ka);
      if (r1 < N) a1 = *(const short8*)(Ag + (size_t)r1*128 + ka);
    }
    #pragma unroll
    for (int nt=0; nt<8; nt++){
      short8 bb = *(const short8*)(Bpk + (size_t)((kk*8 + nt)*64 + lane)*8);
      acc[0][nt] = __builtin_amdgcn_mfma_f32_16x16x32_bf16(a0, bb, acc[0][nt], 0, 0, 0);
      acc[1][nt] = __builtin_amdgcn_mfma_f32_16x16x32_bf16(a1, bb, acc[1][nt], 0, 0, 0);
    }
  }

  float scv[8], shv[8];
  #pragma unroll
  for (int nt=0;nt<8;nt++){ scv[nt] = sc[nt*16 + c]; shv[nt] = sh[nt*16 + c]; }

  #pragma unroll
  for (int mt=0; mt<2; mt++){
    #pragma unroll
    for (int r=0;r<4;r++){
      int row = mb + woff + mt*16 + quad*4 + r;
      if (row < N){
        float u[8];
        #pragma unroll
        for (int nt=0;nt<8;nt++){
          float uu = acc[mt][nt][r]*scv[nt] + shv[nt];
          u[nt] = fmaxf(uu, 0.f);
          outh[(size_t)row*128 + nt*16 + c] = f2bf(u[nt]);
        }
        // fp8(perm) copy: bytes row*128 + c*8 + j hold channel j*16+c
        uint2 q;
        q.x = pk_fp8x4(u[0], u[1], u[2], u[3]);
        q.y = pk_fp8x4(u[4], u[5], u[6], u[7]);
        ((uint2*)outq)[(size_t)row*16 + c] = q;
      }
    }
  }
}

// ---------------- k_fuse1: fused layer-1 (gather haq + GEMM1 + yl mini-GEMM) ----------------

__global__ __launch_bounds__(256, 3) void k_fuse1(
    const uint4* __restrict__ hq4, const int* __restrict__ off, const int* __restrict__ csr,
    const unsigned short* __restrict__ Ag, const unsigned short* __restrict__ Bpk,
    const float* __restrict__ sc, const float* __restrict__ sh,
    const unsigned short* __restrict__ BpkL,
    unsigned short* __restrict__ outh, unsigned* __restrict__ outyl, int n){
  __shared__ uint4 Ms4[128*17];     // 34816 B
  __shared__ uint4 sBL4[1024];      // 16384 B: csr window (gather) -> BpkL stage (yl phase)
  __shared__ int sw[2];
  unsigned short* Ms = (unsigned short*)Ms4;
  int* scsr = (int*)sBL4;
  int t = threadIdx.x;
  int mb = blockIdx.x*128;
  if (t < 2) sw[t] = off[min(mb + t*128, n)];
  __syncthreads();
  int e0b = sw[0];
  int span = sw[1] - e0b;
  int CAPL = 4096;
  for (int i = t; i < span && i < CAPL; i += 256) scsr[i] = csr[e0b + i];
  __syncthreads();

  int lane = t & 63, w = t >> 6;
  int sl = lane & 7;

  // ---- gather phase ----
  #pragma unroll
  for (int it=0; it<4; it++){
    int rk = w*32 + it*8 + (lane >> 3);
    int idx = mb + rk;
    bool valid = idx < n;
    int s0 = valid ? off[idx]   : 0;
    int s1 = valid ? off[idx+1] : 0;
    f32x2 b0={0,0},b1={0,0},b2={0,0},b3={0,0},b4={0,0},b5={0,0},b6={0,0},b7={0,0};
    int e = s0;
    for (; e + 8 <= s1; e += 8){
      int le = e - e0b;
      int i0,i1,i2,i3,i4,i5,i6,i7;
      if (le + 8 <= CAPL){
        i0 = scsr[le];   i1 = scsr[le+1]; i2 = scsr[le+2]; i3 = scsr[le+3];
        i4 = scsr[le+4]; i5 = scsr[le+5]; i6 = scsr[le+6]; i7 = scsr[le+7];
      } else {
        i0 = csr[e];   i1 = csr[e+1]; i2 = csr[e+2]; i3 = csr[e+3];
        i4 = csr[e+4]; i5 = csr[e+5]; i6 = csr[e+6]; i7 = csr[e+7];
      }
      uint4 v0 = hq4[(size_t)i0*8 + sl];
      uint4 v1 = hq4[(size_t)i1*8 + sl];
      uint4 v2 = hq4[(size_t)i2*8 + sl];
      uint4 v3 = hq4[(size_t)i3*8 + sl];
      uint4 v4 = hq4[(size_t)i4*8 + sl];
      uint4 v5 = hq4[(size_t)i5*8 + sl];
      uint4 v6 = hq4[(size_t)i6*8 + sl];
      uint4 v7 = hq4[(size_t)i7*8 + sl];
      ACCP16(v0); ACCP16(v1); ACCP16(v2); ACCP16(v3);
      ACCP16(v4); ACCP16(v5); ACCP16(v6); ACCP16(v7);
    }
    for (; e + 4 <= s1; e += 4){
      int le = e - e0b;
      int i0,i1,i2,i3;
      if (le + 4 <= CAPL){
        i0 = scsr[le]; i1 = scsr[le+1]; i2 = scsr[le+2]; i3 = scsr[le+3];
      } else {
        i0 = csr[e]; i1 = csr[e+1]; i2 = csr[e+2]; i3 = csr[e+3];
      }
      uint4 v0 = hq4[(size_t)i0*8 + sl];
      uint4 v1 = hq4[(size_t)i1*8 + sl];
      uint4 v2 = hq4[(size_t)i2*8 + sl];
      uint4 v3 = hq4[(size_t)i3*8 + sl];
      ACCP16(v0); ACCP16(v1); ACCP16(v2); ACCP16(v3);
    }
    for (; e < s1; e++){
      int le = e - e0b;
      int ii = (le < CAPL) ? scsr[le] : csr[e];
      uint4 v = hq4[(size_t)ii*8 + sl];
      ACCP16(v);
    }
    int d = s1 - s0;
    float inv = 1.0f / (float)(d > 0 ? d : 1);
    uint4 o0, o1;
    o0.x = pack2(b0.x*inv, b0.y*inv);  o0.y = pack2(b1.x*inv, b1.y*inv);
    o0.z = pack2(b2.x*inv, b2.y*inv);  o0.w = pack2(b3.x*inv, b3.y*inv);
    o1.x = pack2(b4.x*inv, b4.y*inv);  o1.y = pack2(b5.x*inv, b5.y*inv);
    o1.z = pack2(b6.x*inv, b6.y*inv);  o1.w = pack2(b7.x*inv, b7.y*inv);
    Ms4[rk*17 + sl*2]     = o0;
    Ms4[rk*17 + sl*2 + 1] = o1;
  }
  __syncthreads();

  // ---- GEMM phase: C = [mean | Ag] @ B (K=256), BN + ReLU ----
  int quad = lane >> 4, c = lane & 15;
  int woff = w*32;
  int r0 = mb + woff + c;
  int r1 = r0 + 16;

  f32x4 acc[2][8];
  #pragma unroll
  for (int mt=0;mt<2;mt++)
    #pragma unroll
    for (int nt=0;nt<8;nt++) acc[mt][nt] = (f32x4){0.f,0.f,0.f,0.f};

  #pragma unroll
  for (int kk=0; kk<8; kk++){
    int ka = (kk & 3)*32 + quad*8;
    short8 a0, a1;
    if (kk < 4){
      a0 = *(const short8*)&Ms[(woff + c)*136 + ka];
      a1 = *(const short8*)&Ms[(woff + c + 16)*136 + ka];
    } else {
      a0 = (short8){0,0,0,0,0,0,0,0}; a1 = (short8){0,0,0,0,0,0,0,0};
      if (r0 < n) a0 = *(const short8*)(Ag + (size_t)r0*128 + ka);
      if (r1 < n) a1 = *(const short8*)(Ag + (size_t)r1*128 + ka);
    }
    #pragma unroll
    for (int nt=0; nt<8; nt++){
      short8 bb = *(const short8*)(Bpk + (size_t)((kk*8 + nt)*64 + lane)*8);
      acc[0][nt] = __builtin_amdgcn_mfma_f32_16x16x32_bf16(a0, bb, acc[0][nt], 0, 0, 0);
      acc[1][nt] = __builtin_amdgcn_mfma_f32_16x16x32_bf16(a1, bb, acc[1][nt], 0, 0, 0);
    }
  }

  float scv[8], shv[8];
  #pragma unroll
  for (int nt=0;nt<8;nt++){ scv[nt] = sc[nt*16 + c]; shv[nt] = sh[nt*16 + c]; }

  __syncthreads();   // all A-reads of Ms done before epilogue overwrites it

  #pragma unroll
  for (int mt=0; mt<2; mt++){
    #pragma unroll
    for (int r=0;r<4;r++){
      int lrow = woff + mt*16 + quad*4 + r;
      int row = mb + lrow;
      if (row < n){
        float u[8];
        #pragma unroll
        for (int nt=0;nt<8;nt++){
          float uu = acc[mt][nt][r]*scv[nt] + shv[nt];
          u[nt] = fmaxf(uu, 0.f);
          outh[(size_t)row*128 + nt*16 + c] = f2bf(u[nt]);
        }
        #pragma unroll
        for (int nt=0;nt<8;nt++) Ms[lrow*136 + nt*16 + c] = f2bf(u[nt]);
      } else {
        #pragma unroll
        for (int nt=0;nt<8;nt++) Ms[lrow*136 + nt*16 + c] = 0;
      }
    }
  }

  // stage BpkL (128x64 bf16 = 1024 uint4) into the csr-window region
  {
    const uint4* sL = (const uint4*)BpkL;
    #pragma unroll
    for (int i=0;i<4;i++) sBL4[i*256 + t] = sL[i*256 + t];
  }
  __syncthreads();
  unsigned short* BsL = (unsigned short*)sBL4;
  f32x4 acc2[2][4];
  #pragma unroll
  for (int mt=0;mt<2;mt++)
    #pragma unroll
    for (int nt=0;nt<4;nt++) acc2[mt][nt] = (f32x4){0.f,0.f,0.f,0.f};
  int r0l = woff + c, r1l = r0l + 16;
  #pragma unroll
  for (int kk=0; kk<4; kk++){
    int ka = kk*32 + quad*8;
    short8 a0 = *(const short8*)&Ms[r0l*136 + ka];
    short8 a1 = *(const short8*)&Ms[r1l*136 + ka];
    #pragma unroll
    for (int nt=0; nt<4; nt++){
      short8 bb = *(const short8*)&BsL[(size_t)((kk*4 + nt)*64 + lane)*8];
      acc2[0][nt] = __builtin_amdgcn_mfma_f32_16x16x32_bf16(a0, bb, acc2[0][nt], 0, 0, 0);
      acc2[1][nt] = __builtin_amdgcn_mfma_f32_16x16x32_bf16(a1, bb, acc2[1][nt], 0, 0, 0);
    }
  }
  #pragma unroll
  for (int mt=0; mt<2; mt++){
    #pragma unroll
    for (int r=0;r<4;r++){
      int row = mb + woff + mt*16 + quad*4 + r;
      if (row < n){
        // fp8(perm2): byte row*64 + c*4 + nt holds channel nt*16+c
        unsigned q  = pk_fp8x4(acc2[0][0][r], acc2[0][1][r], acc2[0][2][r], acc2[0][3][r]);
        unsigned q1 = pk_fp8x4(acc2[1][0][r], acc2[1][1][r], acc2[1][2][r], acc2[1][3][r]);
        outyl[(size_t)row*16 + c] = (mt == 0) ? q : q1;
      }
    }
  }
}

// ---------------- fused layer-3: mean-yl gather (64-dim fp8) + GEMM (h_b@Wr2^T) + BN + L2norm ----------------

#define AGGF_CAP 3072

__global__ __launch_bounds__(256, 3) void k_aggf(
    const uint4* __restrict__ ylq4, const int* __restrict__ off, const int* __restrict__ csr,
    const unsigned short* __restrict__ A0, const unsigned short* __restrict__ BpkR,
    const float* __restrict__ sc, const float* __restrict__ sh,
    float* __restrict__ outf, int n){
  __shared__ unsigned short Ms[128*64];   // 16 KB mean-yl tile (bf16, perm2 positions)
  __shared__ unsigned short Bs[128*64];   // 16 KB BpkR
  __shared__ int scsr[AGGF_CAP];          // 12 KB staged csr window
  __shared__ int sw[2];
  int t = threadIdx.x;
  int mb = blockIdx.x*128;
  if (t < 2) sw[t] = off[min(mb + t*128, n)];
  {
    const uint4* s = (const uint4*)BpkR;
    uint4* d = (uint4*)Bs;
    #pragma unroll
    for (int i=0;i<4;i++) d[i*256 + t] = s[i*256 + t];
  }
  __syncthreads();
  int e0b = sw[0];
  int span = sw[1] - e0b;
  for (int i = t; i < span && i < AGGF_CAP; i += 256) scsr[i] = csr[e0b + i];
  __syncthreads();

  int lane = t & 63, w = t >> 6;
  int sl4 = lane & 3;

  // gather phase: wave w covers ranks [w*32, w*32+32), 16 at a time, 4 lanes x uint4 each
  #pragma unroll
  for (int it=0; it<2; it++){
    int rk = w*32 + it*16 + (lane >> 2);
    int idx = mb + rk;
    bool valid = idx < n;
    int s0 = valid ? off[idx]   : 0;
    int s1 = valid ? off[idx+1] : 0;
    f32x2 b0={0,0},b1={0,0},b2={0,0},b3={0,0},b4={0,0},b5={0,0},b6={0,0},b7={0,0};
    int e = s0;
    for (; e + 8 <= s1; e += 8){
      int le = e - e0b;
      int i0,i1,i2,i3,i4,i5,i6,i7;
      if (le + 8 <= AGGF_CAP){
        i0 = scsr[le];   i1 = scsr[le+1]; i2 = scsr[le+2]; i3 = scsr[le+3];
        i4 = scsr[le+4]; i5 = scsr[le+5]; i6 = scsr[le+6]; i7 = scsr[le+7];
      } else {
        i0 = csr[e];   i1 = csr[e+1]; i2 = csr[e+2]; i3 = csr[e+3];
        i4 = csr[e+4]; i5 = csr[e+5]; i6 = csr[e+6]; i7 = csr[e+7];
      }
      uint4 v0 = ylq4[(size_t)i0*4 + sl4];
      uint4 v1 = ylq4[(size_t)i1*4 + sl4];
      uint4 v2 = ylq4[(size_t)i2*4 + sl4];
      uint4 v3 = ylq4[(size_t)i3*4 + sl4];
      uint4 v4 = ylq4[(size_t)i4*4 + sl4];
      uint4 v5 = ylq4[(size_t)i5*4 + sl4];
      uint4 v6 = ylq4[(size_t)i6*4 + sl4];
      uint4 v7 = ylq4[(size_t)i7*4 + sl4];
      ACCP16(v0); ACCP16(v1); ACCP16(v2); ACCP16(v3);
      ACCP16(v4); ACCP16(v5); ACCP16(v6); ACCP16(v7);
    }
    for (; e + 4 <= s1; e += 4){
      int le = e - e0b;
      int i0,i1,i2,i3;
      if (le + 4 <= AGGF_CAP){
        i0 = scsr[le]; i1 = scsr[le+1]; i2 = scsr[le+2]; i3 = scsr[le+3];
      } else {
        i0 = csr[e]; i1 = csr[e+1]; i2 = csr[e+2]; i3 = csr[e+3];
      }
      uint4 v0 = ylq4[(size_t)i0*4 + sl4];
      uint4 v1 = ylq4[(size_t)i1*4 + sl4];
      uint4 v2 = ylq4[(size_t)i2*4 + sl4];
      uint4 v3 = ylq4[(size_t)i3*4 + sl4];
      ACCP16(v0); ACCP16(v1); ACCP16(v2); ACCP16(v3);
    }
    for (; e < s1; e++){
      int le = e - e0b;
      int ii = (le < AGGF_CAP) ? scsr[le] : csr[e];
      uint4 v = ylq4[(size_t)ii*4 + sl4];
      ACCP16(v);
    }
    int d = s1 - s0;
    float inv = 1.0f / (float)(d > 0 ? d : 1);
    uint4 o0, o1;
    o0.x = pack2(b0.x*inv, b0.y*inv);  o0.y = pack2(b1.x*inv, b1.y*inv);
    o0.z = pack2(b2.x*inv, b2.y*inv);  o0.w = pack2(b3.x*inv, b3.y*inv);
    o1.x = pack2(b4.x*inv, b4.y*inv);  o1.y = pack2(b5.x*inv, b5.y*inv);
    o1.z = pack2(b6.x*inv, b6.y*inv);  o1.w = pack2(b7.x*inv, b7.y*inv);
    ((uint4*)Ms)[rk*8 + sl4*2]     = o0;
    ((uint4*)Ms)[rk*8 + sl4*2 + 1] = o1;
  }
  __syncthreads();

  // GEMM phase: C = h_b @ Wr2^T (K=128), + mean-yl, BN, L2-normalize
  int quad = lane >> 4, c = lane & 15;
  int woff = w*32;
  int r0 = mb + woff + c;
  int r1 = r0 + 16;
  f32x4 acc[2][4];
  #pragma unroll
  for (int mt=0;mt<2;mt++)
    #pragma unroll
    for (int nt=0;nt<4;nt++) acc[mt][nt] = (f32x4){0.f,0.f,0.f,0.f};
  #pragma unroll
  for (int kk=0; kk<4; kk++){
    int ka = kk*32 + quad*8;
    short8 a0 = {0,0,0,0,0,0,0,0}, a1 = {0,0,0,0,0,0,0,0};
    if (r0 < n) a0 = *(const short8*)(A0 + (size_t)r0*128 + ka);
    if (r1 < n) a1 = *(const short8*)(A0 + (size_t)r1*128 + ka);
    #pragma unroll
    for (int nt=0; nt<4; nt++){
      short8 bb = *(const short8*)&Bs[(size_t)((kk*4 + nt)*64 + lane)*8];
      acc[0][nt] = __builtin_amdgcn_mfma_f32_16x16x32_bf16(a0, bb, acc[0][nt], 0, 0, 0);
      acc[1][nt] = __builtin_amdgcn_mfma_f32_16x16x32_bf16(a1, bb, acc[1][nt], 0, 0, 0);
    }
  }

  float scv[4], shv[4];
  #pragma unroll
  for (int nt=0;nt<4;nt++){ scv[nt] = sc[nt*16 + c]; shv[nt] = sh[nt*16 + c]; }

  #pragma unroll
  for (int mt=0; mt<2; mt++){
    #pragma unroll
    for (int r=0;r<4;r++){
      int lr = woff + mt*16 + quad*4 + r;
      int row = mb + lr;
      float v[4];
      float ss = 0.f;
      if (row < n){
        #pragma unroll
        for (int nt=0;nt<4;nt++){
          // Ms holds perm2 positions: channel nt*16+c lives at position c*4+nt
          float u = acc[mt][nt][r] + bf2f(Ms[lr*64 + c*4 + nt]);
          u = u*scv[nt] + shv[nt];
          v[nt] = u;
          ss += u*u;
        }
      } else {
        #pragma unroll
        for (int nt=0;nt<4;nt++) v[nt] = 0.f;
      }
      ss += __shfl_xor(ss, 1, 64);
      ss += __shfl_xor(ss, 2, 64);
      ss += __shfl_xor(ss, 4, 64);
      ss += __shfl_xor(ss, 8, 64);
      float rn = 1.0f / fmaxf(sqrtf(ss), 1e-12f);
      if (row < n){
        #pragma unroll
        for (int nt=0;nt<4;nt++) outf[(size_t)row*64 + nt*16 + c] = v[nt]*rn;
      }
    }
  }
}

// ---------------- launcher ----------------

extern "C" void kernel_launch(void* const* d_in, const int* in_sizes, int n_in,
                              void* d_out, int out_size, void* d_ws, size_t ws_size,
                              hipStream_t stream){
  const float* x = (const float*)d_in[0];
  const int* ei  = (const int*)d_in[1];
  int N = in_sizes[0] / 128;
  int E = in_sizes[1] / 2;
  const int* esrc = ei;
  const int* edst = ei + E;
  int nbuck = CDIV(N, 128);

  const float *Wl[3], *bl[3], *Wr[3], *g[3], *bb[3], *rm[3], *rv[3];
  int dout[3];
  for (int i=0;i<3;i++){
    int base = 2 + 7*i;
    Wl[i]=(const float*)d_in[base];   bl[i]=(const float*)d_in[base+1];
    Wr[i]=(const float*)d_in[base+2]; g[i] =(const float*)d_in[base+3];
    bb[i]=(const float*)d_in[base+4]; rm[i]=(const float*)d_in[base+5];
    rv[i]=(const float*)d_in[base+6];
    dout[i] = in_sizes[base] / 128;
  }

  char* p = (char*)d_ws;
  size_t o = 0;
  auto alloc = [&](size_t bytes)->void*{ void* r = p + o; o += (bytes + 255) & ~(size_t)255; return r; };
  int* bz    = (int*)alloc((size_t)2*nbuck*4);   // bcnt | bcur (one memset)
  int* bcnt  = bz;
  int* bcur  = bz + nbuck;
  int* off   = (int*)alloc((size_t)(N+1)*4);
  int* csr   = (int*)alloc((size_t)E*4);
  unsigned* ebuf = (unsigned*)alloc((size_t)E*4);
  unsigned* xb   = (unsigned*)alloc((size_t)N*64*4);   // bf16 x (natural)
  unsigned* xq   = (unsigned*)alloc((size_t)N*128);    // fp8 x (identity order)
  unsigned* h_a  = (unsigned*)alloc((size_t)N*64*4);   // bf16 h1 (natural)
  unsigned* haq  = (unsigned*)alloc((size_t)N*128);    // fp8 h1 (perm)
  unsigned* h_b  = (unsigned*)alloc((size_t)N*64*4);   // bf16 h2 (natural)
  unsigned* ylb  = (unsigned*)alloc((size_t)N*64);     // fp8 yl (perm2)
  unsigned short* Bpk01[2];
  float* sc[3]; float* sh[3];
  for (int i=0;i<2;i++) Bpk01[i] = (unsigned short*)alloc((size_t)256*dout[i]*2);
  unsigned short* BpkL = (unsigned short*)alloc((size_t)128*dout[2]*2);
  unsigned short* BpkR = (unsigned short*)alloc((size_t)128*dout[2]*2);
  for (int i=0;i<3;i++){
    sc[i] = (float*)alloc((size_t)dout[i]*4);
    sh[i] = (float*)alloc((size_t)dout[i]*4);
  }

  hipMemsetAsync(bz, 0, (size_t)2*nbuck*4, stream);

  WtpArgs wa[4];
  wa[0] = { Wl[0], Wr[0], bl[0], g[0], bb[0], rm[0], rv[0], Bpk01[0], sc[0], sh[0], 8, dout[0], 1, CDIV(256*dout[0]+dout[0],256), 0 };
  wa[1] = { Wl[1], Wr[1], bl[1], g[1], bb[1], rm[1], rv[1], Bpk01[1], sc[1], sh[1], 8, dout[1], 1, CDIV(256*dout[1]+dout[1],256), 1 };
  wa[2] = { Wl[2], nullptr, nullptr, nullptr, nullptr, nullptr, nullptr, BpkL, nullptr, nullptr, 4, dout[2], 0, CDIV(128*dout[2],256), 0 };
  wa[3] = { Wr[2], nullptr, bl[2], g[2], bb[2], rm[2], rv[2], BpkR, sc[2], sh[2], 4, dout[2], 1, CDIV(128*dout[2]+dout[2],256), 0 };

  int castBlocks = CDIV(N*32, 256);
  int histBlocks = CDIV(E, 256*16);
  int prepBlocks = castBlocks + histBlocks + wa[0].nblk + wa[1].nblk + wa[2].nblk + wa[3].nblk;
  k_prep   <<<prepBlocks,256,0,stream>>>(x, N*32, xb, xq, edst, E, bcnt, nbuck, castBlocks, histBlocks,
                                         wa[0], wa[1], wa[2], wa[3]);
  k_bucketA<<<CDIV(E,256*16),256,0,stream>>>(esrc, edst, E, bcnt, bcur, ebuf, nbuck);

  // layer 0 (+ csr build): per-bucket LDS csr -> gather(xq) + GEMM0 -> h_a + haq; writes off/csr for later layers
  k_bfuse<<<nbuck,256,0,stream>>>(ebuf, bcnt, nbuck, E, N, off, csr,
                                  (const uint4*)xq, (const unsigned short*)xb,
                                  Bpk01[0], sc[0], sh[0],
                                  (unsigned short*)h_a, haq);
  // layer 1: fused gather(haq) + GEMM1 + yl mini-GEMM -> h_b + ylb
  k_fuse1<<<nbuck,256,0,stream>>>((const uint4*)haq, off, csr,
                                  (const unsigned short*)h_a, Bpk01[1], sc[1], sh[1], BpkL,
                                  (unsigned short*)h_b, ylb, N);
  // layer 2: fused mean-yl gather + final GEMM + BN + L2norm
  k_aggf<<<nbuck,256,0,stream>>>((const uint4*)ylb, off, csr,
                                 (const unsigned short*)h_b, BpkR, sc[2], sh[2],
                                 (float*)d_out, N);
}

// Round 6
// 226.002 us; speedup vs baseline: 1.0743x; 1.0449x over previous
//
#include <hip/hip_runtime.h>
#include <hip/hip_bf16.h>

#define CDIV(a,b) (((a)+(b)-1)/(b))
#define NBUCK_MAX 512   // 128-node ebuf buckets; supports N up to 65536 (ebuf packing needs N<=65536)
#define FUSE_CAP 1536   // staged csr entries per 64-node bfuse block (mean 1024, +16 sigma)
#define CAPL     4096   // fuse1 csr window (fills the 16KB sBL4 region)
#define AGGF_CAP 2048   // aggf csr window (mean 1024, +32 sigma)

typedef __attribute__((ext_vector_type(8))) short short8;
typedef __attribute__((ext_vector_type(4))) float f32x4;
typedef __attribute__((ext_vector_type(2))) float f32x2;

static __device__ __forceinline__ unsigned short f2bf(float f){
  union { float f; unsigned u; } v; v.f = f;
  unsigned r = v.u + 0x7fffu + ((v.u >> 16) & 1u);   // RNE
  return (unsigned short)(r >> 16);
}
static __device__ __forceinline__ unsigned pack2(float lo, float hi){
  return (unsigned)f2bf(lo) | ((unsigned)f2bf(hi) << 16);
}
static __device__ __forceinline__ float bf2f(unsigned short s){
  union { unsigned u; float f; } v; v.u = ((unsigned)s) << 16; return v.f;
}
// pack 4 f32 -> 4 fp8 e4m3 bytes (byte0=a .. byte3=d)
static __device__ __forceinline__ unsigned pk_fp8x4(float a, float b, float c, float d){
  int v = __builtin_amdgcn_cvt_pk_fp8_f32(a, b, 0, false);
  v = __builtin_amdgcn_cvt_pk_fp8_f32(c, d, v, true);
  return (unsigned)v;
}

// accumulate 16 fp8 bytes (uint4) into f32x2 accumulators b0..b7 (v_pk_add_f32 path)
#define ACCP16(v) { b0 += __builtin_amdgcn_cvt_pk_f32_fp8((int)v.x, false); \
                    b1 += __builtin_amdgcn_cvt_pk_f32_fp8((int)v.x, true);  \
                    b2 += __builtin_amdgcn_cvt_pk_f32_fp8((int)v.y, false); \
                    b3 += __builtin_amdgcn_cvt_pk_f32_fp8((int)v.y, true);  \
                    b4 += __builtin_amdgcn_cvt_pk_f32_fp8((int)v.z, false); \
                    b5 += __builtin_amdgcn_cvt_pk_f32_fp8((int)v.z, true);  \
                    b6 += __builtin_amdgcn_cvt_pk_f32_fp8((int)v.w, false); \
                    b7 += __builtin_amdgcn_cvt_pk_f32_fp8((int)v.w, true); }

// ---------------- weight pack args ----------------
// perm: first-128 K positions hold channel pi(k) = (k&7)*16 + (k>>3) (matches gemm-epilogue fp8 row layout)

struct WtpArgs {
  const float *W0, *W1, *bl, *g, *b, *rm, *rv;
  unsigned short* Bpk; float *sc; float *sh;
  int kblk, dout, do_bn, nblk, perm;
};

static __device__ __forceinline__ void wtp_one(const WtpArgs& a, int idx){
  int NB16 = a.kblk*32*a.dout;
  if (idx < NB16){
    int j = idx & 7, lane = (idx >> 3) & 63, rest = idx >> 9;
    int NT = a.dout >> 4;
    int nt = rest % NT, kk = rest / NT;
    int nn = nt*16 + (lane & 15);
    int k  = kk*32 + ((lane >> 4) * 8) + j;
    float v;
    if (k < 128){
      int kc = a.perm ? (((k & 7) << 4) | (k >> 3)) : k;
      v = a.W0[nn*128 + kc];
    } else {
      v = a.W1[nn*128 + (k - 128)];
    }
    a.Bpk[idx] = f2bf(v);
  } else if (a.do_bn && idx < NB16 + a.dout){
    int jj = idx - NB16;
    float s = a.g[jj] * rsqrtf(a.rv[jj] + 1e-5f);
    a.sc[jj] = s;
    a.sh[jj] = (a.bl[jj] - a.rm[jj]) * s + a.b[jj];
  }
}

// ---------------- prep: cast x->bf16 + x->fp8(identity) in one pass | bucket histogram | weight pack ----------------

__global__ __launch_bounds__(256) void k_prep(const float* __restrict__ x, int n4, unsigned* __restrict__ xb,
                                              unsigned* __restrict__ xq,
                                              const int* __restrict__ dst, int E,
                                              int* __restrict__ bcnt, int nbuck,
                                              int castBlocks, int histBlocks,
                                              WtpArgs a0, WtpArgs a1, WtpArgs a2, WtpArgs a3){
  __shared__ int s[NBUCK_MAX];
  int b = blockIdx.x, t = threadIdx.x;
  if (b < castBlocks){
    int i = b*256 + t;            // i over groups of 4 floats
    if (i < n4){
      float4 v = ((const float4*)x)[i];
      uint2 o; o.x = pack2(v.x, v.y); o.y = pack2(v.z, v.w);
      ((uint2*)xb)[i] = o;
      xq[i] = pk_fp8x4(v.x, v.y, v.z, v.w);    // identity channel order
    }
    return;
  }
  b -= castBlocks;
  if (b < histBlocks){
    for (int i=t;i<nbuck;i+=256) s[i] = 0;
    __syncthreads();
    constexpr int EPT = 16;
    int e0 = b*256*EPT;
    #pragma unroll
    for (int i=0;i<EPT;i++){
      int e = e0 + i*256 + t;
      if (e < E) atomicAdd(&s[dst[e] >> 7], 1);
    }
    __syncthreads();
    for (int i=t;i<nbuck;i+=256){
      int c = s[i];
      if (c > 0) atomicAdd(&bcnt[i], c);
    }
    return;
  }
  b -= histBlocks;
  if (b < a0.nblk){ wtp_one(a0, b*256 + t); return; }
  b -= a0.nblk;
  if (b < a1.nblk){ wtp_one(a1, b*256 + t); return; }
  b -= a1.nblk;
  if (b < a2.nblk){ wtp_one(a2, b*256 + t); return; }
  b -= a2.nblk;
  wtp_one(a3, b*256 + t);
}

// Pass A: bin edges into 128-node buckets; bucket region in ebuf == final csr region.
// Per-block LDS scan of bcnt. Packed entry: (local_dst << 16) | src  (requires N <= 65536)
__global__ __launch_bounds__(256) void k_bucketA(const int* __restrict__ src, const int* __restrict__ dst,
                                                 int E, const int* __restrict__ bcnt,
                                                 int* __restrict__ bcur, unsigned* __restrict__ ebuf, int nbuck){
  __shared__ int scnt[NBUCK_MAX];
  __shared__ int sbase[NBUCK_MAX];
  __shared__ int sboff[NBUCK_MAX];
  __shared__ int ss[256];
  int t = threadIdx.x;
  // exclusive scan of bcnt -> sboff
  {
    int a0 = (2*t   < nbuck) ? bcnt[2*t]   : 0;
    int a1 = (2*t+1 < nbuck) ? bcnt[2*t+1] : 0;
    ss[t] = a0 + a1; __syncthreads();
    for (int d=1; d<256; d<<=1){
      int u = (t>=d) ? ss[t-d] : 0;
      __syncthreads();
      ss[t] += u;
      __syncthreads();
    }
    int excl = ss[t] - (a0 + a1);
    if (2*t   < nbuck) sboff[2*t]   = excl;
    if (2*t+1 < nbuck) sboff[2*t+1] = excl + a0;
  }
  for (int i=t;i<nbuck;i+=256) scnt[i] = 0;
  __syncthreads();
  constexpr int EPT = 16;
  int e0 = blockIdx.x*256*EPT;
  int b[EPT]; unsigned pk[EPT];
  #pragma unroll
  for (int i=0;i<EPT;i++){
    int e = e0 + i*256 + t;
    if (e < E){
      int d = dst[e];
      b[i] = d >> 7;
      pk[i] = ((unsigned)(d & 127) << 16) | (unsigned)src[e];
      atomicAdd(&scnt[b[i]], 1);
    } else b[i] = -1;
  }
  __syncthreads();
  for (int i=t;i<nbuck;i+=256){
    int c = scnt[i];
    sbase[i] = (c > 0) ? atomicAdd(&bcur[i], c) : 0;
    scnt[i] = 0;
  }
  __syncthreads();
  #pragma unroll
  for (int i=0;i<EPT;i++){
    if (b[i] >= 0){
      int p = atomicAdd(&scnt[b[i]], 1);
      ebuf[(size_t)sboff[b[i]] + sbase[b[i]] + p] = pk[i];
    }
  }
}

// ---------------- k_bfuse: csr build + fused layer-0, 64-node blocks (two blocks share a 128-node ebuf window) ----------------

__global__ __launch_bounds__(256, 3) void k_bfuse(
    const unsigned* __restrict__ ebuf, const int* __restrict__ bcnt, int nbuck, int E, int N,
    int* __restrict__ off, int* __restrict__ csr,
    const uint4* __restrict__ xq4, const unsigned short* __restrict__ Ag,
    const unsigned short* __restrict__ Bpk, const float* __restrict__ sc, const float* __restrict__ sh,
    unsigned short* __restrict__ outh, unsigned* __restrict__ outq){
  __shared__ uint4 Ms4[64*17];      // 17408 B mean tile (head reused as sdeg/sabs/cur during csr build)
  __shared__ int scsr[FUSE_CAP];    // 6144 B local csr (this block's 64-node half)
  __shared__ int sEx[NBUCK_MAX];    // 2048 B scan of bcnt
  __shared__ int ss[256];           // 1024 B
  unsigned short* Ms = (unsigned short*)Ms4;
  int* sdeg = (int*)Ms4;            // [128]
  int* sabs = sdeg + 128;           // [129] window-local offsets
  int* cur  = sabs + 129;           // [128]
  int bb_ = blockIdx.x;
  int b = bb_ >> 1, hi = bb_ & 1;
  int t = threadIdx.x;
  // exclusive scan of bcnt -> sEx
  {
    int a0 = (2*t   < nbuck) ? bcnt[2*t]   : 0;
    int a1 = (2*t+1 < nbuck) ? bcnt[2*t+1] : 0;
    ss[t] = a0 + a1; __syncthreads();
    for (int d=1; d<256; d<<=1){
      int u = (t>=d) ? ss[t-d] : 0;
      __syncthreads();
      ss[t] += u;
      __syncthreads();
    }
    int excl = ss[t] - (a0 + a1);
    if (2*t   < nbuck) sEx[2*t]   = excl;
    if (2*t+1 < nbuck) sEx[2*t+1] = excl + a0;
  }
  if (t < 128){ sdeg[t] = 0; cur[t] = 0; }
  __syncthreads();
  int e0 = sEx[b];
  int e1 = (b+1 < nbuck) ? sEx[b+1] : E;
  for (int e = e0 + t; e < e1; e += 256)
    atomicAdd(&sdeg[ebuf[e] >> 16], 1);
  __syncthreads();
  // scan 128 degrees -> window-local starts sabs[0..128]
  for (int d=1; d<128; d<<=1){
    int u = (t < 128 && t >= d) ? sdeg[t-d] : 0;
    __syncthreads();
    if (t < 128) sdeg[t] += u;
    __syncthreads();
  }
  if (t == 0) sabs[0] = 0;
  if (t < 128) sabs[t+1] = sdeg[t];
  __syncthreads();
  int base64 = sabs[hi*64];
  int myTot  = sabs[hi*64 + 64] - base64;
  int n0 = (b << 7) + hi*64;
  int cnt = (N > n0) ? min(64, N - n0) : 0;
  if (cnt > 0 && t <= cnt) off[n0 + t] = e0 + sabs[hi*64 + t];
  // stash this thread's gather ranges before Ms region is reused
  int lane = t & 63, w = t >> 6, sl = lane & 7;
  int gs0[2], gs1[2];
  #pragma unroll
  for (int it=0; it<2; it++){
    int rk = w*16 + it*8 + (lane >> 3);          // local row 0..63
    gs0[it] = sabs[hi*64 + rk] - base64;
    gs1[it] = sabs[hi*64 + rk + 1] - base64;
  }
  bool fits = myTot <= FUSE_CAP;
  // scatter own-half edges into local csr (LDS if fits, else global)
  for (int e = e0 + t; e < e1; e += 256){
    unsigned pr = ebuf[e];
    int ln = (int)(pr >> 16);
    if ((ln >> 6) == hi){
      int p = atomicAdd(&cur[ln], 1);
      int gpos = sabs[ln] + p;                    // position within full window
      int sv = (int)(pr & 0xffffu);
      if (fits) scsr[gpos - base64] = sv;
      else      csr[e0 + gpos] = sv;
    }
  }
  __syncthreads();
  const int* gcsr = csr + e0 + base64;
  if (fits){
    for (int i = t; i < myTot; i += 256) csr[e0 + base64 + i] = scsr[i];
  } else {
    for (int i = t; i < FUSE_CAP; i += 256) scsr[i] = gcsr[i];
    __syncthreads();
  }

  // ---- gather phase: 8 lanes x uint4 per node, 16 nodes/wave ----
  #pragma unroll
  for (int it=0; it<2; it++){
    int rk = w*16 + it*8 + (lane >> 3);
    int s0 = gs0[it], s1 = gs1[it];
    f32x2 b0={0,0},b1={0,0},b2={0,0},b3={0,0},b4={0,0},b5={0,0},b6={0,0},b7={0,0};
    int e = s0;
    for (; e + 8 <= s1; e += 8){
      int i0,i1,i2,i3,i4,i5,i6,i7;
      if (e + 8 <= FUSE_CAP){
        i0 = scsr[e];   i1 = scsr[e+1]; i2 = scsr[e+2]; i3 = scsr[e+3];
        i4 = scsr[e+4]; i5 = scsr[e+5]; i6 = scsr[e+6]; i7 = scsr[e+7];
      } else {
        i0 = gcsr[e];   i1 = gcsr[e+1]; i2 = gcsr[e+2]; i3 = gcsr[e+3];
        i4 = gcsr[e+4]; i5 = gcsr[e+5]; i6 = gcsr[e+6]; i7 = gcsr[e+7];
      }
      uint4 v0 = xq4[(size_t)i0*8 + sl];
      uint4 v1 = xq4[(size_t)i1*8 + sl];
      uint4 v2 = xq4[(size_t)i2*8 + sl];
      uint4 v3 = xq4[(size_t)i3*8 + sl];
      uint4 v4 = xq4[(size_t)i4*8 + sl];
      uint4 v5 = xq4[(size_t)i5*8 + sl];
      uint4 v6 = xq4[(size_t)i6*8 + sl];
      uint4 v7 = xq4[(size_t)i7*8 + sl];
      ACCP16(v0); ACCP16(v1); ACCP16(v2); ACCP16(v3);
      ACCP16(v4); ACCP16(v5); ACCP16(v6); ACCP16(v7);
    }
    for (; e + 4 <= s1; e += 4){
      int i0,i1,i2,i3;
      if (e + 4 <= FUSE_CAP){
        i0 = scsr[e]; i1 = scsr[e+1]; i2 = scsr[e+2]; i3 = scsr[e+3];
      } else {
        i0 = gcsr[e]; i1 = gcsr[e+1]; i2 = gcsr[e+2]; i3 = gcsr[e+3];
      }
      uint4 v0 = xq4[(size_t)i0*8 + sl];
      uint4 v1 = xq4[(size_t)i1*8 + sl];
      uint4 v2 = xq4[(size_t)i2*8 + sl];
      uint4 v3 = xq4[(size_t)i3*8 + sl];
      ACCP16(v0); ACCP16(v1); ACCP16(v2); ACCP16(v3);
    }
    for (; e < s1; e++){
      int ii = (e < FUSE_CAP) ? scsr[e] : gcsr[e];
      uint4 v = xq4[(size_t)ii*8 + sl];
      ACCP16(v);
    }
    int d = s1 - s0;
    float inv = 1.0f / (float)(d > 0 ? d : 1);
    uint4 o0, o1;
    o0.x = pack2(b0.x*inv, b0.y*inv);  o0.y = pack2(b1.x*inv, b1.y*inv);
    o0.z = pack2(b2.x*inv, b2.y*inv);  o0.w = pack2(b3.x*inv, b3.y*inv);
    o1.x = pack2(b4.x*inv, b4.y*inv);  o1.y = pack2(b5.x*inv, b5.y*inv);
    o1.z = pack2(b6.x*inv, b6.y*inv);  o1.w = pack2(b7.x*inv, b7.y*inv);
    Ms4[rk*17 + sl*2]     = o0;
    Ms4[rk*17 + sl*2 + 1] = o1;
  }
  __syncthreads();

  // ---- GEMM phase: C = [mean | Ag] @ B (K=256), BN + ReLU; wave w owns rows [w*16, w*16+16) ----
  int quad = lane >> 4, c = lane & 15;
  int woff = w*16;
  int r0 = n0 + woff + c;

  f32x4 acc[8];
  #pragma unroll
  for (int nt=0;nt<8;nt++) acc[nt] = (f32x4){0.f,0.f,0.f,0.f};

  #pragma unroll
  for (int kk=0; kk<8; kk++){
    int ka = (kk & 3)*32 + quad*8;
    short8 a0;
    if (kk < 4){
      a0 = *(const short8*)&Ms[(woff + c)*136 + ka];
    } else {
      a0 = (short8){0,0,0,0,0,0,0,0};
      if (r0 < N) a0 = *(const short8*)(Ag + (size_t)r0*128 + ka);
    }
    #pragma unroll
    for (int nt=0; nt<8; nt++){
      short8 bb2 = *(const short8*)(Bpk + (size_t)((kk*8 + nt)*64 + lane)*8);
      acc[nt] = __builtin_amdgcn_mfma_f32_16x16x32_bf16(a0, bb2, acc[nt], 0, 0, 0);
    }
  }

  float scv[8], shv[8];
  #pragma unroll
  for (int nt=0;nt<8;nt++){ scv[nt] = sc[nt*16 + c]; shv[nt] = sh[nt*16 + c]; }

  #pragma unroll
  for (int r=0;r<4;r++){
    int row = n0 + woff + quad*4 + r;
    if (row < N){
      float u[8];
      #pragma unroll
      for (int nt=0;nt<8;nt++){
        float uu = acc[nt][r]*scv[nt] + shv[nt];
        u[nt] = fmaxf(uu, 0.f);
        outh[(size_t)row*128 + nt*16 + c] = f2bf(u[nt]);
      }
      // fp8(perm) copy: bytes row*128 + c*8 + j hold channel j*16+c
      uint2 q;
      q.x = pk_fp8x4(u[0], u[1], u[2], u[3]);
      q.y = pk_fp8x4(u[4], u[5], u[6], u[7]);
      ((uint2*)outq)[(size_t)row*16 + c] = q;
    }
  }
}

// ---------------- k_fuse1: fused layer-1 (gather haq + GEMM1 + yl mini-GEMM), 64-node blocks ----------------

__global__ __launch_bounds__(256, 3) void k_fuse1(
    const uint4* __restrict__ hq4, const int* __restrict__ off, const int* __restrict__ csr,
    const unsigned short* __restrict__ Ag, const unsigned short* __restrict__ Bpk,
    const float* __restrict__ sc, const float* __restrict__ sh,
    const unsigned short* __restrict__ BpkL,
    unsigned short* __restrict__ outh, unsigned* __restrict__ outyl, int n){
  __shared__ uint4 Ms4[64*17];      // 17408 B
  __shared__ uint4 sBL4[1024];      // 16384 B: csr window (gather) -> BpkL stage (yl phase)
  __shared__ int sw[2];
  unsigned short* Ms = (unsigned short*)Ms4;
  int* scsr = (int*)sBL4;
  int t = threadIdx.x;
  int n0 = blockIdx.x*64;
  if (t < 2) sw[t] = off[min(n0 + t*64, n)];
  __syncthreads();
  int e0b = sw[0];
  int span = sw[1] - e0b;
  for (int i = t; i < span && i < CAPL; i += 256) scsr[i] = csr[e0b + i];
  __syncthreads();

  int lane = t & 63, w = t >> 6;
  int sl = lane & 7;

  // ---- gather phase: 16 nodes/wave ----
  #pragma unroll
  for (int it=0; it<2; it++){
    int rk = w*16 + it*8 + (lane >> 3);
    int idx = n0 + rk;
    bool valid = idx < n;
    int s0 = valid ? off[idx]   : 0;
    int s1 = valid ? off[idx+1] : 0;
    f32x2 b0={0,0},b1={0,0},b2={0,0},b3={0,0},b4={0,0},b5={0,0},b6={0,0},b7={0,0};
    int e = s0;
    for (; e + 8 <= s1; e += 8){
      int le = e - e0b;
      int i0,i1,i2,i3,i4,i5,i6,i7;
      if (le + 8 <= CAPL){
        i0 = scsr[le];   i1 = scsr[le+1]; i2 = scsr[le+2]; i3 = scsr[le+3];
        i4 = scsr[le+4]; i5 = scsr[le+5]; i6 = scsr[le+6]; i7 = scsr[le+7];
      } else {
        i0 = csr[e];   i1 = csr[e+1]; i2 = csr[e+2]; i3 = csr[e+3];
        i4 = csr[e+4]; i5 = csr[e+5]; i6 = csr[e+6]; i7 = csr[e+7];
      }
      uint4 v0 = hq4[(size_t)i0*8 + sl];
      uint4 v1 = hq4[(size_t)i1*8 + sl];
      uint4 v2 = hq4[(size_t)i2*8 + sl];
      uint4 v3 = hq4[(size_t)i3*8 + sl];
      uint4 v4 = hq4[(size_t)i4*8 + sl];
      uint4 v5 = hq4[(size_t)i5*8 + sl];
      uint4 v6 = hq4[(size_t)i6*8 + sl];
      uint4 v7 = hq4[(size_t)i7*8 + sl];
      ACCP16(v0); ACCP16(v1); ACCP16(v2); ACCP16(v3);
      ACCP16(v4); ACCP16(v5); ACCP16(v6); ACCP16(v7);
    }
    for (; e + 4 <= s1; e += 4){
      int le = e - e0b;
      int i0,i1,i2,i3;
      if (le + 4 <= CAPL){
        i0 = scsr[le]; i1 = scsr[le+1]; i2 = scsr[le+2]; i3 = scsr[le+3];
      } else {
        i0 = csr[e]; i1 = csr[e+1]; i2 = csr[e+2]; i3 = csr[e+3];
      }
      uint4 v0 = hq4[(size_t)i0*8 + sl];
      uint4 v1 = hq4[(size_t)i1*8 + sl];
      uint4 v2 = hq4[(size_t)i2*8 + sl];
      uint4 v3 = hq4[(size_t)i3*8 + sl];
      ACCP16(v0); ACCP16(v1); ACCP16(v2); ACCP16(v3);
    }
    for (; e < s1; e++){
      int le = e - e0b;
      int ii = (le < CAPL) ? scsr[le] : csr[e];
      uint4 v = hq4[(size_t)ii*8 + sl];
      ACCP16(v);
    }
    int d = s1 - s0;
    float inv = 1.0f / (float)(d > 0 ? d : 1);
    uint4 o0, o1;
    o0.x = pack2(b0.x*inv, b0.y*inv);  o0.y = pack2(b1.x*inv, b1.y*inv);
    o0.z = pack2(b2.x*inv, b2.y*inv);  o0.w = pack2(b3.x*inv, b3.y*inv);
    o1.x = pack2(b4.x*inv, b4.y*inv);  o1.y = pack2(b5.x*inv, b5.y*inv);
    o1.z = pack2(b6.x*inv, b6.y*inv);  o1.w = pack2(b7.x*inv, b7.y*inv);
    Ms4[rk*17 + sl*2]     = o0;
    Ms4[rk*17 + sl*2 + 1] = o1;
  }
  __syncthreads();

  // ---- GEMM phase: wave w owns rows [w*16, w*16+16) ----
  int quad = lane >> 4, c = lane & 15;
  int woff = w*16;
  int r0 = n0 + woff + c;

  f32x4 acc[8];
  #pragma unroll
  for (int nt=0;nt<8;nt++) acc[nt] = (f32x4){0.f,0.f,0.f,0.f};

  #pragma unroll
  for (int kk=0; kk<8; kk++){
    int ka = (kk & 3)*32 + quad*8;
    short8 a0;
    if (kk < 4){
      a0 = *(const short8*)&Ms[(woff + c)*136 + ka];
    } else {
      a0 = (short8){0,0,0,0,0,0,0,0};
      if (r0 < n) a0 = *(const short8*)(Ag + (size_t)r0*128 + ka);
    }
    #pragma unroll
    for (int nt=0; nt<8; nt++){
      short8 bb2 = *(const short8*)(Bpk + (size_t)((kk*8 + nt)*64 + lane)*8);
      acc[nt] = __builtin_amdgcn_mfma_f32_16x16x32_bf16(a0, bb2, acc[nt], 0, 0, 0);
    }
  }

  float scv[8], shv[8];
  #pragma unroll
  for (int nt=0;nt<8;nt++){ scv[nt] = sc[nt*16 + c]; shv[nt] = sh[nt*16 + c]; }

  __syncthreads();   // all A-reads of Ms done before epilogue overwrites it

  #pragma unroll
  for (int r=0;r<4;r++){
    int lrow = woff + quad*4 + r;
    int row = n0 + lrow;
    if (row < n){
      float u[8];
      #pragma unroll
      for (int nt=0;nt<8;nt++){
        float uu = acc[nt][r]*scv[nt] + shv[nt];
        u[nt] = fmaxf(uu, 0.f);
        outh[(size_t)row*128 + nt*16 + c] = f2bf(u[nt]);
      }
      #pragma unroll
      for (int nt=0;nt<8;nt++) Ms[lrow*136 + nt*16 + c] = f2bf(u[nt]);
    } else {
      #pragma unroll
      for (int nt=0;nt<8;nt++) Ms[lrow*136 + nt*16 + c] = 0;
    }
  }

  // stage BpkL (128x64 bf16 = 1024 uint4) into the csr-window region
  {
    const uint4* sL = (const uint4*)BpkL;
    #pragma unroll
    for (int i=0;i<4;i++) sBL4[i*256 + t] = sL[i*256 + t];
  }
  __syncthreads();
  unsigned short* BsL = (unsigned short*)sBL4;
  f32x4 acc2[4];
  #pragma unroll
  for (int nt=0;nt<4;nt++) acc2[nt] = (f32x4){0.f,0.f,0.f,0.f};
  int r0l = woff + c;
  #pragma unroll
  for (int kk=0; kk<4; kk++){
    int ka = kk*32 + quad*8;
    short8 a0 = *(const short8*)&Ms[r0l*136 + ka];
    #pragma unroll
    for (int nt=0; nt<4; nt++){
      short8 bb2 = *(const short8*)&BsL[(size_t)((kk*4 + nt)*64 + lane)*8];
      acc2[nt] = __builtin_amdgcn_mfma_f32_16x16x32_bf16(a0, bb2, acc2[nt], 0, 0, 0);
    }
  }
  #pragma unroll
  for (int r=0;r<4;r++){
    int row = n0 + woff + quad*4 + r;
    if (row < n){
      // fp8(perm2): byte row*64 + c*4 + nt holds channel nt*16+c
      unsigned q = pk_fp8x4(acc2[0][r], acc2[1][r], acc2[2][r], acc2[3][r]);
      outyl[(size_t)row*16 + c] = q;
    }
  }
}

// ---------------- fused layer-3: mean-yl gather (64-dim fp8) + GEMM (h_b@Wr2^T) + BN + L2norm, 64-node blocks ----------------

__global__ __launch_bounds__(256, 3) void k_aggf(
    const uint4* __restrict__ ylq4, const int* __restrict__ off, const int* __restrict__ csr,
    const unsigned short* __restrict__ A0, const unsigned short* __restrict__ BpkR,
    const float* __restrict__ sc, const float* __restrict__ sh,
    float* __restrict__ outf, int n){
  __shared__ unsigned short Ms[64*64];    // 8 KB mean-yl tile (bf16, perm2 positions)
  __shared__ unsigned short Bs[128*64];   // 16 KB BpkR
  __shared__ int scsr[AGGF_CAP];          // 8 KB staged csr window
  __shared__ int sw[2];
  int t = threadIdx.x;
  int n0 = blockIdx.x*64;
  if (t < 2) sw[t] = off[min(n0 + t*64, n)];
  {
    const uint4* s = (const uint4*)BpkR;
    uint4* d = (uint4*)Bs;
    #pragma unroll
    for (int i=0;i<4;i++) d[i*256 + t] = s[i*256 + t];
  }
  __syncthreads();
  int e0b = sw[0];
  int span = sw[1] - e0b;
  for (int i = t; i < span && i < AGGF_CAP; i += 256) scsr[i] = csr[e0b + i];
  __syncthreads();

  int lane = t & 63, w = t >> 6;
  int sl4 = lane & 3;

  // gather phase: 16 nodes/wave, 4 lanes x uint4 per node, one iteration
  {
    int rk = w*16 + (lane >> 2);
    int idx = n0 + rk;
    bool valid = idx < n;
    int s0 = valid ? off[idx]   : 0;
    int s1 = valid ? off[idx+1] : 0;
    f32x2 b0={0,0},b1={0,0},b2={0,0},b3={0,0},b4={0,0},b5={0,0},b6={0,0},b7={0,0};
    int e = s0;
    for (; e + 8 <= s1; e += 8){
      int le = e - e0b;
      int i0,i1,i2,i3,i4,i5,i6,i7;
      if (le + 8 <= AGGF_CAP){
        i0 = scsr[le];   i1 = scsr[le+1]; i2 = scsr[le+2]; i3 = scsr[le+3];
        i4 = scsr[le+4]; i5 = scsr[le+5]; i6 = scsr[le+6]; i7 = scsr[le+7];
      } else {
        i0 = csr[e];   i1 = csr[e+1]; i2 = csr[e+2]; i3 = csr[e+3];
        i4 = csr[e+4]; i5 = csr[e+5]; i6 = csr[e+6]; i7 = csr[e+7];
      }
      uint4 v0 = ylq4[(size_t)i0*4 + sl4];
      uint4 v1 = ylq4[(size_t)i1*4 + sl4];
      uint4 v2 = ylq4[(size_t)i2*4 + sl4];
      uint4 v3 = ylq4[(size_t)i3*4 + sl4];
      uint4 v4 = ylq4[(size_t)i4*4 + sl4];
      uint4 v5 = ylq4[(size_t)i5*4 + sl4];
      uint4 v6 = ylq4[(size_t)i6*4 + sl4];
      uint4 v7 = ylq4[(size_t)i7*4 + sl4];
      ACCP16(v0); ACCP16(v1); ACCP16(v2); ACCP16(v3);
      ACCP16(v4); ACCP16(v5); ACCP16(v6); ACCP16(v7);
    }
    for (; e + 4 <= s1; e += 4){
      int le = e - e0b;
      int i0,i1,i2,i3;
      if (le + 4 <= AGGF_CAP){
        i0 = scsr[le]; i1 = scsr[le+1]; i2 = scsr[le+2]; i3 = scsr[le+3];
      } else {
        i0 = csr[e]; i1 = csr[e+1]; i2 = csr[e+2]; i3 = csr[e+3];
      }
      uint4 v0 = ylq4[(size_t)i0*4 + sl4];
      uint4 v1 = ylq4[(size_t)i1*4 + sl4];
      uint4 v2 = ylq4[(size_t)i2*4 + sl4];
      uint4 v3 = ylq4[(size_t)i3*4 + sl4];
      ACCP16(v0); ACCP16(v1); ACCP16(v2); ACCP16(v3);
    }
    for (; e < s1; e++){
      int le = e - e0b;
      int ii = (le < AGGF_CAP) ? scsr[le] : csr[e];
      uint4 v = ylq4[(size_t)ii*4 + sl4];
      ACCP16(v);
    }
    int d = s1 - s0;
    float inv = 1.0f / (float)(d > 0 ? d : 1);
    uint4 o0, o1;
    o0.x = pack2(b0.x*inv, b0.y*inv);  o0.y = pack2(b1.x*inv, b1.y*inv);
    o0.z = pack2(b2.x*inv, b2.y*inv);  o0.w = pack2(b3.x*inv, b3.y*inv);
    o1.x = pack2(b4.x*inv, b4.y*inv);  o1.y = pack2(b5.x*inv, b5.y*inv);
    o1.z = pack2(b6.x*inv, b6.y*inv);  o1.w = pack2(b7.x*inv, b7.y*inv);
    ((uint4*)Ms)[rk*8 + sl4*2]     = o0;
    ((uint4*)Ms)[rk*8 + sl4*2 + 1] = o1;
  }
  __syncthreads();

  // GEMM phase: wave w owns rows [w*16, w*16+16); C = h_b @ Wr2^T (K=128), + mean-yl, BN, L2norm
  int quad = lane >> 4, c = lane & 15;
  int woff = w*16;
  int r0 = n0 + woff + c;
  f32x4 acc[4];
  #pragma unroll
  for (int nt=0;nt<4;nt++) acc[nt] = (f32x4){0.f,0.f,0.f,0.f};
  #pragma unroll
  for (int kk=0; kk<4; kk++){
    int ka = kk*32 + quad*8;
    short8 a0 = {0,0,0,0,0,0,0,0};
    if (r0 < n) a0 = *(const short8*)(A0 + (size_t)r0*128 + ka);
    #pragma unroll
    for (int nt=0; nt<4; nt++){
      short8 bb2 = *(const short8*)&Bs[(size_t)((kk*4 + nt)*64 + lane)*8];
      acc[nt] = __builtin_amdgcn_mfma_f32_16x16x32_bf16(a0, bb2, acc[nt], 0, 0, 0);
    }
  }

  float scv[4], shv[4];
  #pragma unroll
  for (int nt=0;nt<4;nt++){ scv[nt] = sc[nt*16 + c]; shv[nt] = sh[nt*16 + c]; }

  #pragma unroll
  for (int r=0;r<4;r++){
    int lr = woff + quad*4 + r;
    int row = n0 + lr;
    float v[4];
    float ss2 = 0.f;
    if (row < n){
      #pragma unroll
      for (int nt=0;nt<4;nt++){
        // Ms holds perm2 positions: channel nt*16+c lives at position c*4+nt
        float u = acc[nt][r] + bf2f(Ms[lr*64 + c*4 + nt]);
        u = u*scv[nt] + shv[nt];
        v[nt] = u;
        ss2 += u*u;
      }
    } else {
      #pragma unroll
      for (int nt=0;nt<4;nt++) v[nt] = 0.f;
    }
    ss2 += __shfl_xor(ss2, 1, 64);
    ss2 += __shfl_xor(ss2, 2, 64);
    ss2 += __shfl_xor(ss2, 4, 64);
    ss2 += __shfl_xor(ss2, 8, 64);
    float rn = 1.0f / fmaxf(sqrtf(ss2), 1e-12f);
    if (row < n){
      #pragma unroll
      for (int nt=0;nt<4;nt++) outf[(size_t)row*64 + nt*16 + c] = v[nt]*rn;
    }
  }
}

// ---------------- launcher ----------------

extern "C" void kernel_launch(void* const* d_in, const int* in_sizes, int n_in,
                              void* d_out, int out_size, void* d_ws, size_t ws_size,
                              hipStream_t stream){
  const float* x = (const float*)d_in[0];
  const int* ei  = (const int*)d_in[1];
  int N = in_sizes[0] / 128;
  int E = in_sizes[1] / 2;
  const int* esrc = ei;
  const int* edst = ei + E;
  int nbuck = CDIV(N, 128);
  int nb2 = 2*nbuck;

  const float *Wl[3], *bl[3], *Wr[3], *g[3], *bb[3], *rm[3], *rv[3];
  int dout[3];
  for (int i=0;i<3;i++){
    int base = 2 + 7*i;
    Wl[i]=(const float*)d_in[base];   bl[i]=(const float*)d_in[base+1];
    Wr[i]=(const float*)d_in[base+2]; g[i] =(const float*)d_in[base+3];
    bb[i]=(const float*)d_in[base+4]; rm[i]=(const float*)d_in[base+5];
    rv[i]=(const float*)d_in[base+6];
    dout[i] = in_sizes[base] / 128;
  }

  char* p = (char*)d_ws;
  size_t o = 0;
  auto alloc = [&](size_t bytes)->void*{ void* r = p + o; o += (bytes + 255) & ~(size_t)255; return r; };
  int* bz    = (int*)alloc((size_t)2*nbuck*4);   // bcnt | bcur (one memset)
  int* bcnt  = bz;
  int* bcur  = bz + nbuck;
  int* off   = (int*)alloc((size_t)(N+1)*4);
  int* csr   = (int*)alloc((size_t)E*4);
  unsigned* ebuf = (unsigned*)alloc((size_t)E*4);
  unsigned* xb   = (unsigned*)alloc((size_t)N*64*4);   // bf16 x (natural)
  unsigned* xq   = (unsigned*)alloc((size_t)N*128);    // fp8 x (identity order)
  unsigned* h_a  = (unsigned*)alloc((size_t)N*64*4);   // bf16 h1 (natural)
  unsigned* haq  = (unsigned*)alloc((size_t)N*128);    // fp8 h1 (perm)
  unsigned* h_b  = (unsigned*)alloc((size_t)N*64*4);   // bf16 h2 (natural)
  unsigned* ylb  = (unsigned*)alloc((size_t)N*64);     // fp8 yl (perm2)
  unsigned short* Bpk01[2];
  float* sc[3]; float* sh[3];
  for (int i=0;i<2;i++) Bpk01[i] = (unsigned short*)alloc((size_t)256*dout[i]*2);
  unsigned short* BpkL = (unsigned short*)alloc((size_t)128*dout[2]*2);
  unsigned short* BpkR = (unsigned short*)alloc((size_t)128*dout[2]*2);
  for (int i=0;i<3;i++){
    sc[i] = (float*)alloc((size_t)dout[i]*4);
    sh[i] = (float*)alloc((size_t)dout[i]*4);
  }

  hipMemsetAsync(bz, 0, (size_t)2*nbuck*4, stream);

  WtpArgs wa[4];
  wa[0] = { Wl[0], Wr[0], bl[0], g[0], bb[0], rm[0], rv[0], Bpk01[0], sc[0], sh[0], 8, dout[0], 1, CDIV(256*dout[0]+dout[0],256), 0 };
  wa[1] = { Wl[1], Wr[1], bl[1], g[1], bb[1], rm[1], rv[1], Bpk01[1], sc[1], sh[1], 8, dout[1], 1, CDIV(256*dout[1]+dout[1],256), 1 };
  wa[2] = { Wl[2], nullptr, nullptr, nullptr, nullptr, nullptr, nullptr, BpkL, nullptr, nullptr, 4, dout[2], 0, CDIV(128*dout[2],256), 0 };
  wa[3] = { Wr[2], nullptr, bl[2], g[2], bb[2], rm[2], rv[2], BpkR, sc[2], sh[2], 4, dout[2], 1, CDIV(128*dout[2]+dout[2],256), 0 };

  int castBlocks = CDIV(N*32, 256);
  int histBlocks = CDIV(E, 256*16);
  int prepBlocks = castBlocks + histBlocks + wa[0].nblk + wa[1].nblk + wa[2].nblk + wa[3].nblk;
  k_prep   <<<prepBlocks,256,0,stream>>>(x, N*32, xb, xq, edst, E, bcnt, nbuck, castBlocks, histBlocks,
                                         wa[0], wa[1], wa[2], wa[3]);
  k_bucketA<<<CDIV(E,256*16),256,0,stream>>>(esrc, edst, E, bcnt, bcur, ebuf, nbuck);

  // layer 0 (+ csr build): 64-node blocks; writes off/csr for later layers
  k_bfuse<<<nb2,256,0,stream>>>(ebuf, bcnt, nbuck, E, N, off, csr,
                                (const uint4*)xq, (const unsigned short*)xb,
                                Bpk01[0], sc[0], sh[0],
                                (unsigned short*)h_a, haq);
  // layer 1: fused gather(haq) + GEMM1 + yl mini-GEMM -> h_b + ylb
  k_fuse1<<<nb2,256,0,stream>>>((const uint4*)haq, off, csr,
                                (const unsigned short*)h_a, Bpk01[1], sc[1], sh[1], BpkL,
                                (unsigned short*)h_b, ylb, N);
  // layer 2: fused mean-yl gather + final GEMM + BN + L2norm
  k_aggf<<<nb2,256,0,stream>>>((const uint4*)ylb, off, csr,
                               (const unsigned short*)h_b, BpkR, sc[2], sh[2],
                               (float*)d_out, N);
}